// Round 2
// baseline (9600.405 us; speedup 1.0000x reference)
//
#include <hip/hip_runtime.h>
#include <cfloat>
#include <cstdint>

// ---------------- problem constants ----------------
#define HID_   512
#define NH_    2
#define E_     256
#define L1_    100
#define SK1_   25
#define U1_    25
#define L2_    21
#define SK2_   12
#define U2_    12
#define BT_    768
#define DLN_   6144   // 12*HID
#define NGATE_ 4096   // 4*2*HID
#define HC_    1024   // 2*HID

// =====================================================================
// Tuned fp32 GEMM: 128x128 tile, BK=16, 256 threads, 8x8 micro.
// Y[m,n] = X[m,:K] . W[n,:K] + bias[n]  (both K-contiguous, "NT")
// split!=0: N=1536 fused QKV -> col block selects (Wa,Ba,Ya)/(Wb,..)/(Wc,..)
// conv_rows!=0: X row r remapped to ((r/21)*25 + r%21) (conv2 windows)
// LDS row stride 132: writes 2-way (free), compute reads conflict-free.
// Micro-tile: rows ty*8..+8 contiguous, cols tx+16j (strided 16).
// =====================================================================
__global__ __launch_bounds__(256)
void gemm128_kernel(const float* __restrict__ X,
                    const float* __restrict__ Wa, const float* __restrict__ Wb,
                    const float* __restrict__ Wc,
                    const float* __restrict__ Ba, const float* __restrict__ Bb,
                    const float* __restrict__ Bc,
                    float* __restrict__ Ya, float* __restrict__ Yb,
                    float* __restrict__ Yc,
                    int M, int K, int ldx, int ldw, int ldy,
                    int split, int conv_rows)
{
    __shared__ __align__(16) float Xs[16][132];
    __shared__ __align__(16) float Ws[16][132];
    const int tid = threadIdx.x;
    const int row0 = blockIdx.x * 128;
    const int col0 = blockIdx.y * 128;
    const float* Wsel; const float* Bsel; float* Ysel; int coll;
    if (split) {
        int s = col0 >> 9;
        Wsel = (s == 0) ? Wa : ((s == 1) ? Wb : Wc);
        Bsel = (s == 0) ? Ba : ((s == 1) ? Bb : Bc);
        Ysel = (s == 0) ? Ya : ((s == 1) ? Yb : Yc);
        coll = col0 & 511;
    } else { Wsel = Wa; Bsel = Ba; Ysel = Ya; coll = col0; }

    // ---- load mapping: lr = row in tile (0..63, +64), lk = k-quad ----
    const int lr = tid >> 2;
    const int lk = (tid & 3) * 4;
    const int gr0 = row0 + lr, gr1 = row0 + lr + 64;
    const bool v0 = gr0 < M, v1 = gr1 < M;
    size_t xro0 = 0, xro1 = 0;
    if (conv_rows) {
        if (v0) xro0 = ((size_t)(gr0 / 21) * 25 + (size_t)(gr0 % 21)) * (size_t)ldx;
        if (v1) xro1 = ((size_t)(gr1 / 21) * 25 + (size_t)(gr1 % 21)) * (size_t)ldx;
    } else {
        xro0 = (size_t)gr0 * (size_t)ldx;
        xro1 = (size_t)gr1 * (size_t)ldx;
    }
    const float* wr0 = Wsel + (size_t)(coll + lr) * (size_t)ldw;
    const float* wr1 = Wsel + (size_t)(coll + lr + 64) * (size_t)ldw;

    // ---- compute mapping ----
    const int ty = tid >> 4;   // 0..15 -> rows ty*8..+8
    const int tx = tid & 15;   // cols tx + 16*j

    float acc[8][8] = {{0.f}};
    for (int k0 = 0; k0 < K; k0 += 16) {
        float4 z4 = {0.f, 0.f, 0.f, 0.f};
        float4 xa = v0 ? *reinterpret_cast<const float4*>(X + xro0 + k0 + lk) : z4;
        float4 xb = v1 ? *reinterpret_cast<const float4*>(X + xro1 + k0 + lk) : z4;
        float4 wa = *reinterpret_cast<const float4*>(wr0 + k0 + lk);
        float4 wb = *reinterpret_cast<const float4*>(wr1 + k0 + lk);
        __syncthreads();   // previous iteration's compute done
        Xs[lk + 0][lr] = xa.x; Xs[lk + 1][lr] = xa.y; Xs[lk + 2][lr] = xa.z; Xs[lk + 3][lr] = xa.w;
        Xs[lk + 0][lr + 64] = xb.x; Xs[lk + 1][lr + 64] = xb.y; Xs[lk + 2][lr + 64] = xb.z; Xs[lk + 3][lr + 64] = xb.w;
        Ws[lk + 0][lr] = wa.x; Ws[lk + 1][lr] = wa.y; Ws[lk + 2][lr] = wa.z; Ws[lk + 3][lr] = wa.w;
        Ws[lk + 0][lr + 64] = wb.x; Ws[lk + 1][lr + 64] = wb.y; Ws[lk + 2][lr + 64] = wb.z; Ws[lk + 3][lr + 64] = wb.w;
        __syncthreads();
#pragma unroll
        for (int k = 0; k < 16; ++k) {
            float4 a0 = *reinterpret_cast<const float4*>(&Xs[k][ty * 8]);
            float4 a1 = *reinterpret_cast<const float4*>(&Xs[k][ty * 8 + 4]);
            float a[8] = {a0.x, a0.y, a0.z, a0.w, a1.x, a1.y, a1.z, a1.w};
            float b[8];
#pragma unroll
            for (int j = 0; j < 8; ++j) b[j] = Ws[k][tx + 16 * j];
#pragma unroll
            for (int i = 0; i < 8; ++i)
#pragma unroll
                for (int j = 0; j < 8; ++j)
                    acc[i][j] += a[i] * b[j];
        }
    }
    float bv[8];
#pragma unroll
    for (int j = 0; j < 8; ++j) bv[j] = Bsel ? Bsel[coll + tx + 16 * j] : 0.f;
#pragma unroll
    for (int i = 0; i < 8; ++i) {
        int gr = row0 + ty * 8 + i;
        if (gr >= M) continue;
        float* yr = Ysel + (size_t)gr * (size_t)ldy + coll;
#pragma unroll
        for (int j = 0; j < 8; ++j) yr[tx + 16 * j] = acc[i][j] + bv[j];
    }
}

// =====================================================================
// small batched GEMM (kept for the LxL score matrices only):
// 64x64 tile, z-batched with per-head offsets.
// =====================================================================
__global__ __launch_bounds__(256)
void gemm_kernel(const float* __restrict__ X, const float* __restrict__ W,
                 const float* __restrict__ bias, float* __restrict__ Y,
                 int M, int N, int K, int ldx, int ldw, int ldy,
                 size_t bxn, size_t bxh, size_t bwn, size_t bwh, size_t byz,
                 int conv_rows)
{
    __shared__ __align__(16) float Xs[16][68];
    __shared__ __align__(16) float Ws[16][68];
    const int tid = threadIdx.x;
    const int z = blockIdx.z;
    const float* Xb = X + (size_t)(z >> 1) * bxn + (size_t)(z & 1) * bxh;
    const float* Wb = W + (size_t)(z >> 1) * bwn + (size_t)(z & 1) * bwh;
    float* Yb = Y + (size_t)z * byz;
    const int row0 = blockIdx.x * 64;
    const int col0 = blockIdx.y * 64;
    const int lr = tid >> 4;
    const int lc = tid & 15;
    float acc[4][4] = {{0.f}};
    for (int k0 = 0; k0 < K; k0 += 16) {
#pragma unroll
        for (int p = 0; p < 4; ++p) {
            int r = lr + p * 16;
            int gr = row0 + r;
            int gc = col0 + r;
            float xv = 0.f, wv = 0.f;
            if (gr < M) xv = Xb[(size_t)gr * (size_t)ldx + k0 + lc];
            if (gc < N) wv = Wb[(size_t)gc * (size_t)ldw + k0 + lc];
            Xs[lc][r] = xv;
            Ws[lc][r] = wv;
        }
        __syncthreads();
#pragma unroll
        for (int k = 0; k < 16; ++k) {
            float4 a4 = *reinterpret_cast<const float4*>(&Xs[k][lr * 4]);
            float4 b4 = *reinterpret_cast<const float4*>(&Ws[k][lc * 4]);
            float a[4] = {a4.x, a4.y, a4.z, a4.w};
            float b[4] = {b4.x, b4.y, b4.z, b4.w};
#pragma unroll
            for (int i = 0; i < 4; ++i)
#pragma unroll
                for (int j = 0; j < 4; ++j)
                    acc[i][j] += a[i] * b[j];
        }
        __syncthreads();
    }
#pragma unroll
    for (int i = 0; i < 4; ++i) {
        int gr = row0 + lr * 4 + i;
        if (gr >= M) continue;
#pragma unroll
        for (int j = 0; j < 4; ++j) {
            int gc = col0 + lc * 4 + j;
            if (gc >= N) continue;
            float v = acc[i][j];
            if (bias) v += bias[gc];
            Yb[(size_t)gr * (size_t)ldy + gc] = v;
        }
    }
}

// =====================================================================
// conv1: input (768,104,10,8) select wt + positional enc -> VALID conv K=5
// =====================================================================
__global__ __launch_bounds__(256)
void conv1_kernel(const float* __restrict__ input, const int* __restrict__ wtp,
                  const float* __restrict__ w, const float* __restrict__ bias,
                  float* __restrict__ H, int n0)
{
    __shared__ float xs[50];
    const int bid = blockIdx.x;
    const int nloc = bid / L1_;
    const int l = bid % L1_;
    const size_t n = (size_t)n0 + nloc;
    const int tid = threadIdx.x;
    if (tid < 50) {
        int i = tid / 5, k = tid % 5;
        int t = l + k;
        float xv;
        if (i < 8) {
            xv = input[((n * 104 + t) * 10 + wtp[0]) * 8 + i];
        } else {
            float pos = (float)t / 104.0f;
            xv = (i == 8) ? sinf(pos) : cosf(pos);
        }
        xs[i * 5 + k] = xv;
    }
    __syncthreads();
    for (int o = tid; o < HID_; o += 256) {
        const float* wr = w + (size_t)o * 50;
        float acc = bias[o];
#pragma unroll
        for (int j = 0; j < 50; ++j) acc += wr[j] * xs[j];
        H[((size_t)nloc * L1_ + l) * HID_ + o] = acc;
    }
}

// =====================================================================
// sparsity measure m + stable descending top-U (matches jax.lax.top_k)
// =====================================================================
__global__ __launch_bounds__(128)
void mtop_kernel(const float* __restrict__ S, const int* __restrict__ idx,
                 int* __restrict__ top, int L, int SK, int U)
{
    __shared__ float mv[128];
    __shared__ float rv[128];
    __shared__ int   ri[128];
    const int z = blockIdx.x;
    const int tid = threadIdx.x;
    float m = -FLT_MAX;
    if (tid < L) {
        const float* row = S + ((size_t)z * L + tid) * L;
        float mx = -FLT_MAX, sm = 0.f;
        for (int s = 0; s < SK; ++s) {
            float v = row[idx[tid * SK + s]];
            mx = fmaxf(mx, v);
            sm += v;
        }
        m = mx - sm / (float)L;
    }
    mv[tid] = m;
    __syncthreads();
    for (int u = 0; u < U; ++u) {
        rv[tid] = mv[tid]; ri[tid] = tid;
        __syncthreads();
        for (int off = 64; off > 0; off >>= 1) {
            if (tid < off) {
                float v2 = rv[tid + off]; int i2 = ri[tid + off];
                if (v2 > rv[tid] || (v2 == rv[tid] && i2 < ri[tid])) { rv[tid] = v2; ri[tid] = i2; }
            }
            __syncthreads();
        }
        if (tid == 0) { top[(size_t)z * U + u] = ri[0]; mv[ri[0]] = -FLT_MAX; }
        __syncthreads();
    }
}

// =====================================================================
// softmax(selected score row) with SUFFIX-SUMMED weights dotted against
// RAW V  (identity: attn @ cumsum(V) == suffix_sum(attn) @ V) -- the
// separate cumsum pass over V is eliminated entirely.
// output in torch-.view() interleave: slot=h*U+u -> row slot/2, col (slot&1)*256+e
// =====================================================================
__global__ __launch_bounds__(256)
void ctx_kernel(const float* __restrict__ S, const int* __restrict__ top,
                const float* __restrict__ V, float* __restrict__ C,
                int L, int U)
{
    __shared__ float attn[128];
    __shared__ float red[256];
    const int bid = blockIdx.x;
    const int u = bid % U;
    const int rem = bid / U;
    const int h = rem & 1;
    const int n = rem >> 1;
    const int tid = threadIdx.x;
    const int z = n * 2 + h;
    const int r = top[(size_t)z * U + u];
    const float* srow = S + ((size_t)z * L + r) * L;
    float v = (tid < L) ? srow[tid] * 0.0625f : -FLT_MAX;   // 1/sqrt(256)
    red[tid] = v;
    __syncthreads();
    for (int off = 128; off > 0; off >>= 1) { if (tid < off) red[tid] = fmaxf(red[tid], red[tid + off]); __syncthreads(); }
    float mx = red[0];
    __syncthreads();
    float e = (tid < L) ? expf(v - mx) : 0.f;
    red[tid] = e;
    __syncthreads();
    for (int off = 128; off > 0; off >>= 1) { if (tid < off) red[tid] += red[tid + off]; __syncthreads(); }
    float inv = 1.f / red[0];
    if (tid < 128) attn[tid] = (tid < L) ? e * inv : 0.f;
    __syncthreads();
    // suffix scan: attn[l] <- sum_{s>=l} attn[s]   (7 Hillis-Steele steps)
    for (int off = 1; off < 128; off <<= 1) {
        float add = 0.f;
        if (tid < 128 && tid + off < 128) add = attn[tid + off];
        __syncthreads();
        if (tid < 128) attn[tid] += add;
        __syncthreads();
    }
    float acc = 0.f;
    const float* vb = V + (size_t)n * L * HID_ + h * E_ + tid;
    for (int s = 0; s < L; ++s) acc += attn[s] * vb[(size_t)s * HID_];
    int slot = h * U + u;
    int rr = slot >> 1, cc = (slot & 1) * E_ + tid;
    C[((size_t)n * U + rr) * HID_ + cc] = acc;
}

// 32x32 tiled transpose: A (R,C) -> At (C,R)
__global__ __launch_bounds__(256)
void transpose_kernel(const float* __restrict__ A, float* __restrict__ At, int R, int C)
{
    __shared__ float ts[32][33];
    int cb = blockIdx.x * 32, rb = blockIdx.y * 32;
    int tx = threadIdx.x & 31, ty = threadIdx.x >> 5;
    for (int i = ty; i < 32; i += 8) ts[i][tx] = A[(size_t)(rb + i) * C + cb + tx];
    __syncthreads();
    for (int i = ty; i < 32; i += 8) At[(size_t)(cb + i) * R + rb + tx] = ts[tx][i];
}

// conv2 weight (O,I,K) -> (O,K,I)
__global__ void w2t_kernel(const float* __restrict__ w, float* __restrict__ wt)
{
    int idx = blockIdx.x * 256 + threadIdx.x;
    if (idx >= 512 * 5 * 512) return;
    int i = idx & 511;
    int rem = idx >> 9;
    int k = rem % 5;
    int o = rem / 5;
    wt[idx] = w[((size_t)o * 512 + i) * 5 + k];
}

__global__ void biasg_kernel(const float* __restrict__ a, const float* __restrict__ b, float* __restrict__ o)
{
    int i = blockIdx.x * 256 + threadIdx.x;
    if (i < NGATE_) o[i] = a[i] + b[i];
}

// LayerNorm(6144) in place; one block per row
__global__ __launch_bounds__(256)
void ln_kernel(float* __restrict__ X, const float* __restrict__ g, const float* __restrict__ b)
{
    __shared__ float lred[4];
    const int row = blockIdx.x;
    const int tid = threadIdx.x;
    float* x = X + (size_t)row * DLN_;
    float v[24];
#pragma unroll
    for (int i = 0; i < 24; ++i) v[i] = x[tid + i * 256];
    float s = 0.f;
#pragma unroll
    for (int i = 0; i < 24; ++i) s += v[i];
    for (int off = 32; off > 0; off >>= 1) s += __shfl_down(s, off);
    int lane = tid & 63, wid = tid >> 6;
    if (lane == 0) lred[wid] = s;
    __syncthreads();
    float mu = (lred[0] + lred[1] + lred[2] + lred[3]) / (float)DLN_;
    float q = 0.f;
#pragma unroll
    for (int i = 0; i < 24; ++i) { float d = v[i] - mu; q += d * d; }
    for (int off = 32; off > 0; off >>= 1) q += __shfl_down(q, off);
    __syncthreads();
    if (lane == 0) lred[wid] = q;
    __syncthreads();
    float var = (lred[0] + lred[1] + lred[2] + lred[3]) / (float)DLN_;
    float rstd = 1.0f / sqrtf(var + 1e-5f);
#pragma unroll
    for (int i = 0; i < 24; ++i) {
        int c = tid + i * 256;
        x[c] = (v[i] - mu) * rstd * g[c] + b[c];
    }
}

// =====================================================================
// one LSTM time step
// =====================================================================
__global__ __launch_bounds__(256)
void lstm_step_kernel(const float* __restrict__ Gx, const float* __restrict__ WhhT,
                      const float* __restrict__ hp, const float* __restrict__ cp,
                      float* __restrict__ hn, float* __restrict__ cn, int t)
{
    __shared__ __align__(16) float hs[16 * HC_];
    __shared__ float pbuf[4096];
    const int tid = threadIdx.x;
    {
        const float4* hp4 = (const float4*)hp;
        float4* hs4 = (float4*)hs;
        for (int i = tid; i < 16 * HC_ / 4; i += 256) hs4[i] = hp4[i];
    }
    __syncthreads();
    const int jjl = tid & 7;
    const int g = (tid >> 3) & 3;
    const int ks = tid >> 5;
    const int jj = blockIdx.x * 8 + jjl;
    float acc[16];
#pragma unroll
    for (int b = 0; b < 16; ++b) acc[b] = 0.f;
    const float* wp = WhhT + (size_t)(ks * 128) * NGATE_ + (size_t)g * HC_ + jj;
    const float* hb = hs + ks * 128;
    for (int k = 0; k < 128; ++k) {
        float w = wp[(size_t)k * NGATE_];
#pragma unroll
        for (int b = 0; b < 16; ++b) acc[b] += hb[b * HC_ + k] * w;
    }
#pragma unroll
    for (int b = 0; b < 16; ++b) pbuf[((g * 8 + jjl) * 16 + b) * 8 + ks] = acc[b];
    __syncthreads();
    if (tid < 128) {
        int b = tid >> 3, jl = tid & 7;
        int jjo = blockIdx.x * 8 + jl;
        float G[4];
#pragma unroll
        for (int g2 = 0; g2 < 4; ++g2) {
            float s = 0.f;
#pragma unroll
            for (int k2 = 0; k2 < 8; ++k2) s += pbuf[((g2 * 8 + jl) * 16 + b) * 8 + k2];
            G[g2] = s + Gx[((size_t)(b * 48 + t)) * NGATE_ + g2 * HC_ + jjo];
        }
        float ig = 1.f / (1.f + expf(-G[0]));
        float fg = 1.f / (1.f + expf(-G[1]));
        float gg = tanhf(G[2]);
        float og = 1.f / (1.f + expf(-G[3]));
        float c = fg * cp[b * HC_ + jjo] + ig * gg;
        float h = og * tanhf(c);
        cn[b * HC_ + jjo] = c;
        hn[b * HC_ + jjo] = h;
    }
}

__global__ __launch_bounds__(64)
void final_kernel(const float* __restrict__ hn, const float* __restrict__ W,
                  const float* __restrict__ bias, float* __restrict__ out)
{
    int o = blockIdx.x;
    int bb = o / 24, p = o % 24;
    int lane = threadIdx.x;
    float acc = 0.f;
    for (int k = lane; k < HC_; k += 64) acc += hn[(size_t)bb * HC_ + k] * W[(size_t)p * HC_ + k];
    for (int off = 32; off > 0; off >>= 1) acc += __shfl_down(acc, off);
    if (lane == 0) out[o] = acc + bias[p];
}

// ---------------------------------------------------------------------
struct WSLayout {
    float *O2, *Gx, *WhhT, *w2t, *biasG, *hbuf, *cbuf;
    float *H1, *Q1, *K1, *V1, *S1, *CT1, *O1;
    float *H2, *Q2, *K2, *V2, *S2, *CT2;
    int *top1, *top2;
};

static size_t ws_layout(char* base, size_t NC, WSLayout& w)
{
    size_t off = 0;
    auto A = [&](size_t nfloats) -> float* {
        float* p = (float*)(base + off);
        off += ((nfloats * 4 + 255) & ~(size_t)255);
        return p;
    };
    w.O2 = A((size_t)BT_ * 12 * 512);
    w.Gx = A((size_t)BT_ * NGATE_);
    w.WhhT = A((size_t)HC_ * NGATE_);
    w.w2t = A((size_t)512 * 5 * 512);
    w.biasG = A(NGATE_);
    w.hbuf = A(2 * 16 * HC_);
    w.cbuf = A(2 * 16 * HC_);
    w.H1 = A(NC * 51200); w.Q1 = A(NC * 51200); w.K1 = A(NC * 51200); w.V1 = A(NC * 51200);
    w.S1 = A(NC * 20000); w.CT1 = A(NC * 12800); w.O1 = A(NC * 12800);
    w.H2 = A(NC * 10752); w.Q2 = A(NC * 10752); w.K2 = A(NC * 10752); w.V2 = A(NC * 10752);
    w.S2 = A(NC * 882);  w.CT2 = A(NC * 6144);
    w.top1 = (int*)A(NC * 50);
    w.top2 = (int*)A(NC * 24);
    return off;
}

extern "C" void kernel_launch(void* const* d_in, const int* in_sizes, int n_in,
                              void* d_out, int out_size, void* d_ws, size_t ws_size,
                              hipStream_t stream)
{
    const float* input = (const float*)d_in[0];
    const int*   wtp   = (const int*)d_in[2];
    const int*   idx1  = (const int*)d_in[3];
    const int*   idx2  = (const int*)d_in[4];
    const float* c1w   = (const float*)d_in[5];
    const float* c1b   = (const float*)d_in[6];
    const float* c2w   = (const float*)d_in[7];
    const float* c2b   = (const float*)d_in[8];
    const float* a1qw = (const float*)d_in[9];  const float* a1qb = (const float*)d_in[10];
    const float* a1kw = (const float*)d_in[11]; const float* a1kb = (const float*)d_in[12];
    const float* a1vw = (const float*)d_in[13]; const float* a1vb = (const float*)d_in[14];
    const float* a1ow = (const float*)d_in[15]; const float* a1ob = (const float*)d_in[16];
    const float* a2qw = (const float*)d_in[17]; const float* a2qb = (const float*)d_in[18];
    const float* a2kw = (const float*)d_in[19]; const float* a2kb = (const float*)d_in[20];
    const float* a2vw = (const float*)d_in[21]; const float* a2vb = (const float*)d_in[22];
    const float* a2ow = (const float*)d_in[23]; const float* a2ob = (const float*)d_in[24];
    const float* lng  = (const float*)d_in[25]; const float* lnb = (const float*)d_in[26];
    const float* wih  = (const float*)d_in[27]; const float* whh = (const float*)d_in[28];
    const float* bih  = (const float*)d_in[29]; const float* bhh = (const float*)d_in[30];
    const float* finw = (const float*)d_in[31]; const float* finb = (const float*)d_in[32];
    float* out = (float*)d_out;

    static const size_t cand[5] = {768, 384, 192, 128, 64};
    size_t NC = 64;
    WSLayout W;
    for (int i = 0; i < 5; ++i) {
        WSLayout tmp;
        size_t need = ws_layout((char*)d_ws, cand[i], tmp);
        if (need <= ws_size) { NC = cand[i]; break; }
    }
    ws_layout((char*)d_ws, NC, W);

    // big-GEMM helper (single output)
    auto g128 = [&](const float* X, const float* Wt, const float* bias, float* Y,
                    int M, int N, int K, int ldx, int ldw, int ldy, int conv_rows) {
        dim3 grid((M + 127) / 128, N / 128, 1);
        hipLaunchKernelGGL(gemm128_kernel, grid, dim3(256), 0, stream,
                           X, Wt, nullptr, nullptr, bias, nullptr, nullptr,
                           Y, nullptr, nullptr, M, K, ldx, ldw, ldy, 0, conv_rows);
    };
    // fused QKV
    auto g128qkv = [&](const float* X, int M,
                       const float* wq, const float* bq, float* Q,
                       const float* wk, const float* bk, float* Kx,
                       const float* wv, const float* bv, float* V) {
        dim3 grid((M + 127) / 128, 1536 / 128, 1);
        hipLaunchKernelGGL(gemm128_kernel, grid, dim3(256), 0, stream,
                           X, wq, wk, wv, bq, bk, bv, Q, Kx, V,
                           M, 512, 512, 512, 512, 1, 0);
    };
    auto gemmS = [&](const float* X, const float* Wt, float* Y, int L, int Z) {
        dim3 grid((L + 63) / 64, (L + 63) / 64, Z);
        hipLaunchKernelGGL(gemm_kernel, grid, dim3(256), 0, stream,
                           X, Wt, nullptr, Y, L, L, E_, 512, 512, L,
                           (size_t)L * 512, E_, (size_t)L * 512, E_, (size_t)L * L, 0);
    };

    hipLaunchKernelGGL(transpose_kernel, dim3(HC_ / 32, NGATE_ / 32), dim3(256), 0, stream,
                       whh, W.WhhT, NGATE_, HC_);
    hipLaunchKernelGGL(w2t_kernel, dim3((512 * 5 * 512 + 255) / 256), dim3(256), 0, stream, c2w, W.w2t);
    hipLaunchKernelGGL(biasg_kernel, dim3((NGATE_ + 255) / 256), dim3(256), 0, stream, bih, bhh, W.biasG);

    const int nchunks = BT_ / (int)NC;
    for (int ch = 0; ch < nchunks; ++ch) {
        const int n0 = ch * (int)NC;
        const int M1 = (int)NC * L1_;
        hipLaunchKernelGGL(conv1_kernel, dim3((int)NC * L1_), dim3(256), 0, stream,
                           input, wtp, c1w, c1b, W.H1, n0);
        g128qkv(W.H1, M1, a1qw, a1qb, W.Q1, a1kw, a1kb, W.K1, a1vw, a1vb, W.V1);
        gemmS(W.Q1, W.K1, W.S1, L1_, (int)NC * 2);
        hipLaunchKernelGGL(mtop_kernel, dim3((int)NC * 2), dim3(128), 0, stream,
                           W.S1, idx1, W.top1, L1_, SK1_, U1_);
        hipLaunchKernelGGL(ctx_kernel, dim3((int)NC * 2 * U1_), dim3(256), 0, stream,
                           W.S1, W.top1, W.V1, W.CT1, L1_, U1_);
        g128(W.CT1, a1ow, a1ob, W.O1, (int)NC * U1_, 512, 512, 512, 512, 512, 0);
        // conv2 as GEMM over overlapped windows of O1
        g128(W.O1, W.w2t, c2b, W.H2, (int)NC * L2_, 512, 2560, 512, 2560, 512, 1);
        const int M2 = (int)NC * L2_;
        g128qkv(W.H2, M2, a2qw, a2qb, W.Q2, a2kw, a2kb, W.K2, a2vw, a2vb, W.V2);
        gemmS(W.Q2, W.K2, W.S2, L2_, (int)NC * 2);
        hipLaunchKernelGGL(mtop_kernel, dim3((int)NC * 2), dim3(128), 0, stream,
                           W.S2, idx2, W.top2, L2_, SK2_, U2_);
        hipLaunchKernelGGL(ctx_kernel, dim3((int)NC * 2 * U2_), dim3(256), 0, stream,
                           W.S2, W.top2, W.V2, W.CT2, L2_, U2_);
        g128(W.CT2, a2ow, a2ob, W.O2 + (size_t)n0 * 12 * 512,
             (int)NC * U2_, 512, 512, 512, 512, 512, 0);
    }

    hipLaunchKernelGGL(ln_kernel, dim3(BT_), dim3(256), 0, stream, W.O2, lng, lnb);
    g128(W.O2, wih, W.biasG, W.Gx, BT_, NGATE_, DLN_, DLN_, DLN_, NGATE_, 0);

    hipMemsetAsync(W.hbuf, 0, 2 * 16 * HC_ * sizeof(float), stream);
    hipMemsetAsync(W.cbuf, 0, 2 * 16 * HC_ * sizeof(float), stream);
    for (int t = 0; t < 48; ++t) {
        float* hp = W.hbuf + (t & 1) * 16 * HC_;
        float* hn = W.hbuf + ((t + 1) & 1) * 16 * HC_;
        float* cp = W.cbuf + (t & 1) * 16 * HC_;
        float* cn = W.cbuf + ((t + 1) & 1) * 16 * HC_;
        hipLaunchKernelGGL(lstm_step_kernel, dim3(128), dim3(256), 0, stream,
                           W.Gx, W.WhhT, hp, cp, hn, cn, t);
    }
    hipLaunchKernelGGL(final_kernel, dim3(16 * 24), dim3(64), 0, stream,
                       W.hbuf, finw, finb, out);
}

// Round 3
// 6801.330 us; speedup vs baseline: 1.4115x; 1.4115x over previous
//
#include <hip/hip_runtime.h>
#include <cfloat>
#include <cstdint>

// ---------------- problem constants ----------------
#define HID_   512
#define NH_    2
#define E_     256
#define L1_    100
#define SK1_   25
#define U1_    25
#define L2_    21
#define SK2_   12
#define U2_    12
#define BT_    768
#define DLN_   6144   // 12*HID
#define NGATE_ 4096   // 4*2*HID
#define HC_    1024   // 2*HID

typedef unsigned short u16;
typedef __attribute__((ext_vector_type(8))) short short8v;
typedef __attribute__((ext_vector_type(4))) short short4v;
typedef __attribute__((ext_vector_type(4))) float f32x4;

// ---- bf16 triple-split helpers (RNE) ----
__device__ __forceinline__ u16 bfr_(float x) {
    unsigned u = __float_as_uint(x);
    return (u16)((u + 0x7fffu + ((u >> 16) & 1u)) >> 16);
}
__device__ __forceinline__ float bf2f_(u16 h) {
    return __uint_as_float(((unsigned)h) << 16);
}
__device__ __forceinline__ void split3_(float x, short& h, short& m, short& l) {
    u16 hh = bfr_(x); float r = x - bf2f_(hh);
    u16 mm = bfr_(r); float r2 = r - bf2f_(mm);
    u16 ll = bfr_(r2);
    h = (short)hh; m = (short)mm; l = (short)ll;
}

// fp32 (N,K) -> three bf16 planes at dst[p*plane + off + i]
__global__ __launch_bounds__(256)
void cvt3_kernel(const float* __restrict__ src, u16* __restrict__ dst,
                 size_t n, size_t plane, size_t off)
{
    size_t i = ((size_t)blockIdx.x * 256 + threadIdx.x) * 4;
    if (i >= n) return;
    float4 v = *(const float4*)(src + i);
    float x[4] = {v.x, v.y, v.z, v.w};
    short h[4], m[4], l[4];
#pragma unroll
    for (int e = 0; e < 4; ++e) split3_(x[e], h[e], m[e], l[e]);
    *(short4v*)(dst + off + i)             = *(short4v*)h;
    *(short4v*)(dst + plane + off + i)     = *(short4v*)m;
    *(short4v*)(dst + 2 * plane + off + i) = *(short4v*)l;
}

// =====================================================================
// MFMA GEMM (NT): Y[m,n] = X[m,:K] . W[n,:K] + bias[n]
// X fp32 (split in staging), W pre-split bf16 planes [3][Nw][K].
// 128x128 tile, BK=32, 4 waves (2x2), each wave 64x64 via 16x16x32 MFMA,
// 6-term bf16x3 product (hh,hm,mh,mm,hl,lh) -> ~2^-26 relative accuracy.
// split!=0: N=1536 fused QKV (W3 fused; Y/bias per 512-col group).
// conv_rows!=0: X row r -> (r/21)*25 + r%21 (conv2 overlapped windows).
// LDS 16B-slot XOR swizzle (slot ^= row&3) to cut ds_read conflicts.
// =====================================================================
#define MFMA_(acc, a, b) \
    asm volatile("v_mfma_f32_16x16x32_bf16 %0, %1, %2, %0" : "+v"(acc) : "v"(a), "v"(b))

__global__ __launch_bounds__(256)
void gemm_mfma(const float* __restrict__ X, const u16* __restrict__ W3,
               const float* __restrict__ Ba, const float* __restrict__ Bb,
               const float* __restrict__ Bc,
               float* __restrict__ Ya, float* __restrict__ Yb, float* __restrict__ Yc,
               int M, int K, int ldx, int ldy, size_t wplane, int split, int conv_rows)
{
    __shared__ short Xs[3][128 * 32];
    __shared__ short Ws[3][128 * 32];
    const int tid = threadIdx.x;
    const int row0 = blockIdx.x * 128;
    const int col0 = blockIdx.y * 128;
    const float* Bsel; float* Ysel; int coll;
    if (split) {
        int s = col0 >> 9;
        Bsel = (s == 0) ? Ba : ((s == 1) ? Bb : Bc);
        Ysel = (s == 0) ? Ya : ((s == 1) ? Yb : Yc);
        coll = col0 & 511;
    } else { Bsel = Ba; Ysel = Ya; coll = col0; }

    // staging mapping: thread -> (row 0..127, k-quad 0/16)
    const int srow = tid >> 1;
    const int skq = (tid & 1) * 16;
    int gr = row0 + srow; if (gr >= M) gr = M - 1;
    size_t xro = conv_rows ? ((size_t)(gr / 21) * 25 + (size_t)(gr % 21)) * (size_t)ldx
                           : (size_t)gr * (size_t)ldx;
    const float* xp = X + xro + skq;
    const u16* wp = W3 + (size_t)(col0 + srow) * (size_t)K + skq;
    const int sl0 = ((skq >> 3) + 0) ^ (srow & 3);   // swizzled 16B slots
    const int sl1 = ((skq >> 3) + 1) ^ (srow & 3);
    const int xw0 = srow * 32 + sl0 * 8;
    const int xw1 = srow * 32 + sl1 * 8;

    const int wave = tid >> 6, lane = tid & 63;
    const int wr = (wave >> 1) * 64, wc = (wave & 1) * 64;
    const int r16 = lane & 15, kb = lane >> 4;

    f32x4 acc[4][4];
#pragma unroll
    for (int i = 0; i < 4; ++i)
#pragma unroll
        for (int j = 0; j < 4; ++j) acc[i][j] = (f32x4){0.f, 0.f, 0.f, 0.f};

    for (int k0 = 0; k0 < K; k0 += 32) {
        // ---- load + split X (fp32 -> 3 bf16 planes in regs) ----
        float xv[16];
        *(float4*)&xv[0]  = *(const float4*)(xp + k0);
        *(float4*)&xv[4]  = *(const float4*)(xp + k0 + 4);
        *(float4*)&xv[8]  = *(const float4*)(xp + k0 + 8);
        *(float4*)&xv[12] = *(const float4*)(xp + k0 + 12);
        short hb[16], mb[16], lb[16];
#pragma unroll
        for (int e = 0; e < 16; ++e) split3_(xv[e], hb[e], mb[e], lb[e]);
        // ---- load W planes (already bf16) ----
        short8v wv[3][2];
#pragma unroll
        for (int p = 0; p < 3; ++p) {
            wv[p][0] = *(const short8v*)(wp + (size_t)p * wplane + k0);
            wv[p][1] = *(const short8v*)(wp + (size_t)p * wplane + k0 + 8);
        }
        __syncthreads();   // previous iteration's frag reads done
        *(short8v*)&Xs[0][xw0] = *(short8v*)&hb[0];
        *(short8v*)&Xs[0][xw1] = *(short8v*)&hb[8];
        *(short8v*)&Xs[1][xw0] = *(short8v*)&mb[0];
        *(short8v*)&Xs[1][xw1] = *(short8v*)&mb[8];
        *(short8v*)&Xs[2][xw0] = *(short8v*)&lb[0];
        *(short8v*)&Xs[2][xw1] = *(short8v*)&lb[8];
#pragma unroll
        for (int p = 0; p < 3; ++p) {
            *(short8v*)&Ws[p][xw0] = wv[p][0];
            *(short8v*)&Ws[p][xw1] = wv[p][1];
        }
        __syncthreads();
        // ---- fragments + MFMA ----
        short8v Bf[4][3];
#pragma unroll
        for (int j = 0; j < 4; ++j) {
            int c = wc + j * 16 + r16;
            int ad = c * 32 + ((kb ^ (c & 3)) * 8);
#pragma unroll
            for (int p = 0; p < 3; ++p) Bf[j][p] = *(short8v*)&Ws[p][ad];
        }
#pragma unroll
        for (int i = 0; i < 4; ++i) {
            int rrow = wr + i * 16 + r16;
            int ad = rrow * 32 + ((kb ^ (rrow & 3)) * 8);
            short8v Ah = *(short8v*)&Xs[0][ad];
            short8v Am = *(short8v*)&Xs[1][ad];
            short8v Al = *(short8v*)&Xs[2][ad];
#pragma unroll
            for (int j = 0; j < 4; ++j) MFMA_(acc[i][j], Ah, Bf[j][0]);   // h*h
#pragma unroll
            for (int j = 0; j < 4; ++j) MFMA_(acc[i][j], Ah, Bf[j][1]);   // h*m
#pragma unroll
            for (int j = 0; j < 4; ++j) MFMA_(acc[i][j], Am, Bf[j][0]);   // m*h
#pragma unroll
            for (int j = 0; j < 4; ++j) MFMA_(acc[i][j], Am, Bf[j][1]);   // m*m
#pragma unroll
            for (int j = 0; j < 4; ++j) MFMA_(acc[i][j], Ah, Bf[j][2]);   // h*l
#pragma unroll
            for (int j = 0; j < 4; ++j) MFMA_(acc[i][j], Al, Bf[j][0]);   // l*h
        }
    }
    asm volatile("s_nop 7\n\ts_nop 7" :::);   // MFMA -> VALU read hazard pad
    // epilogue: C/D layout col=lane&15, row=(lane>>4)*4+reg  [m89]
#pragma unroll
    for (int j = 0; j < 4; ++j) {
        int gc = coll + wc + j * 16 + r16;
        float bval = Bsel ? Bsel[gc] : 0.f;
#pragma unroll
        for (int i = 0; i < 4; ++i) {
#pragma unroll
            for (int r = 0; r < 4; ++r) {
                int grow = row0 + wr + i * 16 + kb * 4 + r;
                if (grow < M) Ysel[(size_t)grow * (size_t)ldy + gc] = acc[i][j][r] + bval;
            }
        }
    }
}

// =====================================================================
// fp32 64x64 GEMM (scores + full fallback path). NT, z-batched,
// optional conv2 window remap.
// =====================================================================
__global__ __launch_bounds__(256)
void gemm_kernel(const float* __restrict__ X, const float* __restrict__ W,
                 const float* __restrict__ bias, float* __restrict__ Y,
                 int M, int N, int K, int ldx, int ldw, int ldy,
                 size_t bxn, size_t bxh, size_t bwn, size_t bwh, size_t byz,
                 int conv_rows)
{
    __shared__ __align__(16) float Xs[16][68];
    __shared__ __align__(16) float Ws[16][68];
    const int tid = threadIdx.x;
    const int z = blockIdx.z;
    const float* Xb = X + (size_t)(z >> 1) * bxn + (size_t)(z & 1) * bxh;
    const float* Wb = W + (size_t)(z >> 1) * bwn + (size_t)(z & 1) * bwh;
    float* Yb = Y + (size_t)z * byz;
    const int row0 = blockIdx.x * 64;
    const int col0 = blockIdx.y * 64;
    const int lr = tid >> 4;
    const int lc = tid & 15;
    float acc[4][4] = {{0.f}};
    for (int k0 = 0; k0 < K; k0 += 16) {
#pragma unroll
        for (int p = 0; p < 4; ++p) {
            int r = lr + p * 16;
            int grr = row0 + r;
            int gcc = col0 + r;
            float xv = 0.f, wvv = 0.f;
            if (grr < M) {
                size_t ro = conv_rows ? ((size_t)(grr / 21) * 25 + (size_t)(grr % 21)) * (size_t)ldx
                                      : (size_t)grr * (size_t)ldx;
                xv = Xb[ro + k0 + lc];
            }
            if (gcc < N) wvv = Wb[(size_t)gcc * (size_t)ldw + k0 + lc];
            Xs[lc][r] = xv;
            Ws[lc][r] = wvv;
        }
        __syncthreads();
#pragma unroll
        for (int k = 0; k < 16; ++k) {
            float4 a4 = *reinterpret_cast<const float4*>(&Xs[k][lr * 4]);
            float4 b4 = *reinterpret_cast<const float4*>(&Ws[k][lc * 4]);
            float a[4] = {a4.x, a4.y, a4.z, a4.w};
            float b[4] = {b4.x, b4.y, b4.z, b4.w};
#pragma unroll
            for (int i = 0; i < 4; ++i)
#pragma unroll
                for (int j = 0; j < 4; ++j)
                    acc[i][j] += a[i] * b[j];
        }
        __syncthreads();
    }
#pragma unroll
    for (int i = 0; i < 4; ++i) {
        int grr = row0 + lr * 4 + i;
        if (grr >= M) continue;
#pragma unroll
        for (int j = 0; j < 4; ++j) {
            int gcc = col0 + lc * 4 + j;
            if (gcc >= N) continue;
            float v = acc[i][j];
            if (bias) v += bias[gcc];
            Yb[(size_t)grr * (size_t)ldy + gcc] = v;
        }
    }
}

// =====================================================================
// conv1: input (768,104,10,8) select wt + positional enc -> VALID conv K=5
// =====================================================================
__global__ __launch_bounds__(256)
void conv1_kernel(const float* __restrict__ input, const int* __restrict__ wtp,
                  const float* __restrict__ w, const float* __restrict__ bias,
                  float* __restrict__ H, int n0)
{
    __shared__ float xs[50];
    const int bid = blockIdx.x;
    const int nloc = bid / L1_;
    const int l = bid % L1_;
    const size_t n = (size_t)n0 + nloc;
    const int tid = threadIdx.x;
    if (tid < 50) {
        int i = tid / 5, k = tid % 5;
        int t = l + k;
        float xv;
        if (i < 8) {
            xv = input[((n * 104 + t) * 10 + wtp[0]) * 8 + i];
        } else {
            float pos = (float)t / 104.0f;
            xv = (i == 8) ? sinf(pos) : cosf(pos);
        }
        xs[i * 5 + k] = xv;
    }
    __syncthreads();
    for (int o = tid; o < HID_; o += 256) {
        const float* wr = w + (size_t)o * 50;
        float acc = bias[o];
#pragma unroll
        for (int j = 0; j < 50; ++j) acc += wr[j] * xs[j];
        H[((size_t)nloc * L1_ + l) * HID_ + o] = acc;
    }
}

// =====================================================================
// sparsity measure m + stable descending top-U (matches jax.lax.top_k)
// =====================================================================
__global__ __launch_bounds__(128)
void mtop_kernel(const float* __restrict__ S, const int* __restrict__ idx,
                 int* __restrict__ top, int L, int SK, int U)
{
    __shared__ float mv[128];
    __shared__ float rv[128];
    __shared__ int   ri[128];
    const int z = blockIdx.x;
    const int tid = threadIdx.x;
    float m = -FLT_MAX;
    if (tid < L) {
        const float* row = S + ((size_t)z * L + tid) * L;
        float mx = -FLT_MAX, sm = 0.f;
        for (int s = 0; s < SK; ++s) {
            float v = row[idx[tid * SK + s]];
            mx = fmaxf(mx, v);
            sm += v;
        }
        m = mx - sm / (float)L;
    }
    mv[tid] = m;
    __syncthreads();
    for (int u = 0; u < U; ++u) {
        rv[tid] = mv[tid]; ri[tid] = tid;
        __syncthreads();
        for (int off = 64; off > 0; off >>= 1) {
            if (tid < off) {
                float v2 = rv[tid + off]; int i2 = ri[tid + off];
                if (v2 > rv[tid] || (v2 == rv[tid] && i2 < ri[tid])) { rv[tid] = v2; ri[tid] = i2; }
            }
            __syncthreads();
        }
        if (tid == 0) { top[(size_t)z * U + u] = ri[0]; mv[ri[0]] = -FLT_MAX; }
        __syncthreads();
    }
}

// =====================================================================
// softmax(selected row) -> suffix-sum weights -> dot raw V
// (attn @ cumsum(V) == suffix_sum(attn) @ V) ; .view() interleave output
// =====================================================================
__global__ __launch_bounds__(256)
void ctx_kernel(const float* __restrict__ S, const int* __restrict__ top,
                const float* __restrict__ V, float* __restrict__ C,
                int L, int U)
{
    __shared__ float attn[128];
    __shared__ float red[256];
    const int bid = blockIdx.x;
    const int u = bid % U;
    const int rem = bid / U;
    const int h = rem & 1;
    const int n = rem >> 1;
    const int tid = threadIdx.x;
    const int z = n * 2 + h;
    const int r = top[(size_t)z * U + u];
    const float* srow = S + ((size_t)z * L + r) * L;
    float v = (tid < L) ? srow[tid] * 0.0625f : -FLT_MAX;   // 1/sqrt(256)
    red[tid] = v;
    __syncthreads();
    for (int off = 128; off > 0; off >>= 1) { if (tid < off) red[tid] = fmaxf(red[tid], red[tid + off]); __syncthreads(); }
    float mx = red[0];
    __syncthreads();
    float e = (tid < L) ? expf(v - mx) : 0.f;
    red[tid] = e;
    __syncthreads();
    for (int off = 128; off > 0; off >>= 1) { if (tid < off) red[tid] += red[tid + off]; __syncthreads(); }
    float inv = 1.f / red[0];
    if (tid < 128) attn[tid] = (tid < L) ? e * inv : 0.f;
    __syncthreads();
    for (int off = 1; off < 128; off <<= 1) {
        float add = 0.f;
        if (tid < 128 && tid + off < 128) add = attn[tid + off];
        __syncthreads();
        if (tid < 128) attn[tid] += add;
        __syncthreads();
    }
    float acc = 0.f;
    const float* vb = V + (size_t)n * L * HID_ + h * E_ + tid;
    for (int s = 0; s < L; ++s) acc += attn[s] * vb[(size_t)s * HID_];
    int slot = h * U + u;
    int rr = slot >> 1, cc = (slot & 1) * E_ + tid;
    C[((size_t)n * U + rr) * HID_ + cc] = acc;
}

// 32x32 tiled transpose: A (R,C) -> At (C,R)
__global__ __launch_bounds__(256)
void transpose_kernel(const float* __restrict__ A, float* __restrict__ At, int R, int C)
{
    __shared__ float ts[32][33];
    int cb = blockIdx.x * 32, rb = blockIdx.y * 32;
    int tx = threadIdx.x & 31, ty = threadIdx.x >> 5;
    for (int i = ty; i < 32; i += 8) ts[i][tx] = A[(size_t)(rb + i) * C + cb + tx];
    __syncthreads();
    for (int i = ty; i < 32; i += 8) At[(size_t)(cb + i) * R + rb + tx] = ts[tx][i];
}

// conv2 weight (O,I,K) -> (O,K,I)
__global__ void w2t_kernel(const float* __restrict__ w, float* __restrict__ wt)
{
    int idx = blockIdx.x * 256 + threadIdx.x;
    if (idx >= 512 * 5 * 512) return;
    int i = idx & 511;
    int rem = idx >> 9;
    int k = rem % 5;
    int o = rem / 5;
    wt[idx] = w[((size_t)o * 512 + i) * 5 + k];
}

__global__ void biasg_kernel(const float* __restrict__ a, const float* __restrict__ b, float* __restrict__ o)
{
    int i = blockIdx.x * 256 + threadIdx.x;
    if (i < NGATE_) o[i] = a[i] + b[i];
}

// LayerNorm(6144) in place; one block per row
__global__ __launch_bounds__(256)
void ln_kernel(float* __restrict__ X, const float* __restrict__ g, const float* __restrict__ b)
{
    __shared__ float lred[4];
    const int row = blockIdx.x;
    const int tid = threadIdx.x;
    float* x = X + (size_t)row * DLN_;
    float v[24];
#pragma unroll
    for (int i = 0; i < 24; ++i) v[i] = x[tid + i * 256];
    float s = 0.f;
#pragma unroll
    for (int i = 0; i < 24; ++i) s += v[i];
    for (int off = 32; off > 0; off >>= 1) s += __shfl_down(s, off);
    int lane = tid & 63, wid = tid >> 6;
    if (lane == 0) lred[wid] = s;
    __syncthreads();
    float mu = (lred[0] + lred[1] + lred[2] + lred[3]) / (float)DLN_;
    float q = 0.f;
#pragma unroll
    for (int i = 0; i < 24; ++i) { float d = v[i] - mu; q += d * d; }
    for (int off = 32; off > 0; off >>= 1) q += __shfl_down(q, off);
    __syncthreads();
    if (lane == 0) lred[wid] = q;
    __syncthreads();
    float var = (lred[0] + lred[1] + lred[2] + lred[3]) / (float)DLN_;
    float rstd = 1.0f / sqrtf(var + 1e-5f);
#pragma unroll
    for (int i = 0; i < 24; ++i) {
        int c = tid + i * 256;
        x[c] = (v[i] - mu) * rstd * g[c] + b[c];
    }
}

// =====================================================================
// one LSTM time step
// =====================================================================
__global__ __launch_bounds__(256)
void lstm_step_kernel(const float* __restrict__ Gx, const float* __restrict__ WhhT,
                      const float* __restrict__ hp, const float* __restrict__ cp,
                      float* __restrict__ hn, float* __restrict__ cn, int t)
{
    __shared__ __align__(16) float hs[16 * HC_];
    __shared__ float pbuf[4096];
    const int tid = threadIdx.x;
    {
        const float4* hp4 = (const float4*)hp;
        float4* hs4 = (float4*)hs;
        for (int i = tid; i < 16 * HC_ / 4; i += 256) hs4[i] = hp4[i];
    }
    __syncthreads();
    const int jjl = tid & 7;
    const int g = (tid >> 3) & 3;
    const int ks = tid >> 5;
    const int jj = blockIdx.x * 8 + jjl;
    float acc[16];
#pragma unroll
    for (int b = 0; b < 16; ++b) acc[b] = 0.f;
    const float* wp = WhhT + (size_t)(ks * 128) * NGATE_ + (size_t)g * HC_ + jj;
    const float* hb = hs + ks * 128;
    for (int k = 0; k < 128; ++k) {
        float w = wp[(size_t)k * NGATE_];
#pragma unroll
        for (int b = 0; b < 16; ++b) acc[b] += hb[b * HC_ + k] * w;
    }
#pragma unroll
    for (int b = 0; b < 16; ++b) pbuf[((g * 8 + jjl) * 16 + b) * 8 + ks] = acc[b];
    __syncthreads();
    if (tid < 128) {
        int b = tid >> 3, jl = tid & 7;
        int jjo = blockIdx.x * 8 + jl;
        float G[4];
#pragma unroll
        for (int g2 = 0; g2 < 4; ++g2) {
            float s = 0.f;
#pragma unroll
            for (int k2 = 0; k2 < 8; ++k2) s += pbuf[((g2 * 8 + jl) * 16 + b) * 8 + k2];
            G[g2] = s + Gx[((size_t)(b * 48 + t)) * NGATE_ + g2 * HC_ + jjo];
        }
        float ig = 1.f / (1.f + expf(-G[0]));
        float fg = 1.f / (1.f + expf(-G[1]));
        float gg = tanhf(G[2]);
        float og = 1.f / (1.f + expf(-G[3]));
        float c = fg * cp[b * HC_ + jjo] + ig * gg;
        float h = og * tanhf(c);
        cn[b * HC_ + jjo] = c;
        hn[b * HC_ + jjo] = h;
    }
}

__global__ __launch_bounds__(64)
void final_kernel(const float* __restrict__ hn, const float* __restrict__ W,
                  const float* __restrict__ bias, float* __restrict__ out)
{
    int o = blockIdx.x;
    int bb = o / 24, p = o % 24;
    int lane = threadIdx.x;
    float acc = 0.f;
    for (int k = lane; k < HC_; k += 64) acc += hn[(size_t)bb * HC_ + k] * W[(size_t)p * HC_ + k];
    for (int off = 32; off > 0; off >>= 1) acc += __shfl_down(acc, off);
    if (lane == 0) out[o] = acc + bias[p];
}

// ---------------------------------------------------------------------
struct WSLayout {
    float *O2, *Gx, *WhhT, *w2t, *biasG, *hbuf, *cbuf;
    float *H1, *Q1, *K1, *V1, *S1, *CT1, *O1;
    float *H2, *Q2, *K2, *V2, *S2, *CT2;
    int *top1, *top2;
    u16 *w3_qkv1, *w3_o1, *w3_c2, *w3_qkv2, *w3_o2, *w3_ih;
};

static size_t ws_layout(char* base, size_t NC, int with_w3, WSLayout& w)
{
    size_t off = 0;
    auto A = [&](size_t nfloats) -> float* {
        float* p = (float*)(base + off);
        off += ((nfloats * 4 + 255) & ~(size_t)255);
        return p;
    };
    auto AU = [&](size_t nush) -> u16* {
        u16* p = (u16*)(base + off);
        off += ((nush * 2 + 255) & ~(size_t)255);
        return p;
    };
    if (with_w3) {
        w.w3_qkv1 = AU((size_t)3 * 1536 * 512);
        w.w3_o1   = AU((size_t)3 * 512 * 512);
        w.w3_c2   = AU((size_t)3 * 512 * 2560);
        w.w3_qkv2 = AU((size_t)3 * 1536 * 512);
        w.w3_o2   = AU((size_t)3 * 512 * 512);
        w.w3_ih   = AU((size_t)3 * 4096 * 6144);
    } else {
        w.w3_qkv1 = w.w3_o1 = w.w3_c2 = w.w3_qkv2 = w.w3_o2 = w.w3_ih = nullptr;
    }
    w.O2 = A((size_t)BT_ * 12 * 512);
    w.Gx = A((size_t)BT_ * NGATE_);
    w.WhhT = A((size_t)HC_ * NGATE_);
    w.w2t = A((size_t)512 * 5 * 512);
    w.biasG = A(NGATE_);
    w.hbuf = A(2 * 16 * HC_);
    w.cbuf = A(2 * 16 * HC_);
    w.H1 = A(NC * 51200); w.Q1 = A(NC * 51200); w.K1 = A(NC * 51200); w.V1 = A(NC * 51200);
    w.S1 = A(NC * 20000); w.CT1 = A(NC * 12800); w.O1 = A(NC * 12800);
    w.H2 = A(NC * 10752); w.Q2 = A(NC * 10752); w.K2 = A(NC * 10752); w.V2 = A(NC * 10752);
    w.S2 = A(NC * 882);  w.CT2 = A(NC * 6144);
    w.top1 = (int*)A(NC * 50);
    w.top2 = (int*)A(NC * 24);
    return off;
}

extern "C" void kernel_launch(void* const* d_in, const int* in_sizes, int n_in,
                              void* d_out, int out_size, void* d_ws, size_t ws_size,
                              hipStream_t stream)
{
    const float* input = (const float*)d_in[0];
    const int*   wtp   = (const int*)d_in[2];
    const int*   idx1  = (const int*)d_in[3];
    const int*   idx2  = (const int*)d_in[4];
    const float* c1w   = (const float*)d_in[5];
    const float* c1b   = (const float*)d_in[6];
    const float* c2w   = (const float*)d_in[7];
    const float* c2b   = (const float*)d_in[8];
    const float* a1qw = (const float*)d_in[9];  const float* a1qb = (const float*)d_in[10];
    const float* a1kw = (const float*)d_in[11]; const float* a1kb = (const float*)d_in[12];
    const float* a1vw = (const float*)d_in[13]; const float* a1vb = (const float*)d_in[14];
    const float* a1ow = (const float*)d_in[15]; const float* a1ob = (const float*)d_in[16];
    const float* a2qw = (const float*)d_in[17]; const float* a2qb = (const float*)d_in[18];
    const float* a2kw = (const float*)d_in[19]; const float* a2kb = (const float*)d_in[20];
    const float* a2vw = (const float*)d_in[21]; const float* a2vb = (const float*)d_in[22];
    const float* a2ow = (const float*)d_in[23]; const float* a2ob = (const float*)d_in[24];
    const float* lng  = (const float*)d_in[25]; const float* lnb = (const float*)d_in[26];
    const float* wih  = (const float*)d_in[27]; const float* whh = (const float*)d_in[28];
    const float* bih  = (const float*)d_in[29]; const float* bhh = (const float*)d_in[30];
    const float* finw = (const float*)d_in[31]; const float* finb = (const float*)d_in[32];
    float* out = (float*)d_out;

    static const size_t cand[5] = {768, 384, 192, 128, 64};
    size_t NC = 64;
    int use_mfma = 0;
    WSLayout W;
    for (int i = 0; i < 5; ++i) {
        WSLayout tmp;
        if (ws_layout((char*)d_ws, cand[i], 1, tmp) <= ws_size) { NC = cand[i]; use_mfma = 1; break; }
    }
    if (!use_mfma) {
        for (int i = 0; i < 5; ++i) {
            WSLayout tmp;
            if (ws_layout((char*)d_ws, cand[i], 0, tmp) <= ws_size) { NC = cand[i]; break; }
        }
    }
    ws_layout((char*)d_ws, NC, use_mfma, W);

    auto gemm64 = [&](const float* X, const float* Wt, const float* bias, float* Y,
                      int M, int N, int K, int ldx, int ldw, int ldy,
                      int Z, size_t bxn, size_t bxh, size_t bwn, size_t bwh, size_t byz,
                      int conv_rows) {
        dim3 grid((M + 63) / 64, (N + 63) / 64, Z);
        hipLaunchKernelGGL(gemm_kernel, grid, dim3(256), 0, stream,
                           X, Wt, bias, Y, M, N, K, ldx, ldw, ldy,
                           bxn, bxh, bwn, bwh, byz, conv_rows);
    };
    auto gemmS = [&](const float* X, const float* Wt, float* Y, int L, int Z) {
        dim3 grid((L + 63) / 64, (L + 63) / 64, Z);
        hipLaunchKernelGGL(gemm_kernel, grid, dim3(256), 0, stream,
                           X, Wt, nullptr, Y, L, L, E_, 512, 512, L,
                           (size_t)L * 512, E_, (size_t)L * 512, E_, (size_t)L * L, 0);
    };
    auto cvt3 = [&](const float* src, u16* dst, size_t n, size_t plane, size_t off) {
        hipLaunchKernelGGL(cvt3_kernel, dim3((unsigned)((n / 4 + 255) / 256)), dim3(256), 0, stream,
                           src, dst, n, plane, off);
    };
    auto gM = [&](const float* X, const u16* W3, const float* bias, float* Y,
                  int M, int N, int K, int ldx, int ldy, size_t wplane, int conv_rows) {
        dim3 grid((M + 127) / 128, N / 128, 1);
        hipLaunchKernelGGL(gemm_mfma, grid, dim3(256), 0, stream,
                           X, W3, bias, nullptr, nullptr, Y, nullptr, nullptr,
                           M, K, ldx, ldy, wplane, 0, conv_rows);
    };
    auto gMqkv = [&](const float* X, int M, const u16* W3,
                     const float* bq, float* Q, const float* bk, float* Kx,
                     const float* bv, float* V) {
        dim3 grid((M + 127) / 128, 1536 / 128, 1);
        hipLaunchKernelGGL(gemm_mfma, grid, dim3(256), 0, stream,
                           X, W3, bq, bk, bv, Q, Kx, V,
                           M, 512, 512, 512, (size_t)1536 * 512, 1, 0);
    };

    // ---- one-time (per call) prep ----
    hipLaunchKernelGGL(transpose_kernel, dim3(HC_ / 32, NGATE_ / 32), dim3(256), 0, stream,
                       whh, W.WhhT, NGATE_, HC_);
    hipLaunchKernelGGL(w2t_kernel, dim3((512 * 5 * 512 + 255) / 256), dim3(256), 0, stream, c2w, W.w2t);
    hipLaunchKernelGGL(biasg_kernel, dim3((NGATE_ + 255) / 256), dim3(256), 0, stream, bih, bhh, W.biasG);
    if (use_mfma) {
        const size_t p512 = (size_t)512 * 512, pq = (size_t)1536 * 512;
        cvt3(a1qw, W.w3_qkv1, p512, pq, 0);
        cvt3(a1kw, W.w3_qkv1, p512, pq, p512);
        cvt3(a1vw, W.w3_qkv1, p512, pq, 2 * p512);
        cvt3(a1ow, W.w3_o1, p512, p512, 0);
        cvt3(W.w2t, W.w3_c2, (size_t)512 * 2560, (size_t)512 * 2560, 0);
        cvt3(a2qw, W.w3_qkv2, p512, pq, 0);
        cvt3(a2kw, W.w3_qkv2, p512, pq, p512);
        cvt3(a2vw, W.w3_qkv2, p512, pq, 2 * p512);
        cvt3(a2ow, W.w3_o2, p512, p512, 0);
        cvt3(wih, W.w3_ih, (size_t)4096 * 6144, (size_t)4096 * 6144, 0);
    }

    const int nchunks = BT_ / (int)NC;
    for (int ch = 0; ch < nchunks; ++ch) {
        const int n0 = ch * (int)NC;
        const int M1 = (int)NC * L1_;
        const int M2 = (int)NC * L2_;
        hipLaunchKernelGGL(conv1_kernel, dim3((int)NC * L1_), dim3(256), 0, stream,
                           input, wtp, c1w, c1b, W.H1, n0);
        if (use_mfma) {
            gMqkv(W.H1, M1, W.w3_qkv1, a1qb, W.Q1, a1kb, W.K1, a1vb, W.V1);
        } else {
            gemm64(W.H1, a1qw, a1qb, W.Q1, M1, 512, 512, 512, 512, 512, 1, 0, 0, 0, 0, 0, 0);
            gemm64(W.H1, a1kw, a1kb, W.K1, M1, 512, 512, 512, 512, 512, 1, 0, 0, 0, 0, 0, 0);
            gemm64(W.H1, a1vw, a1vb, W.V1, M1, 512, 512, 512, 512, 512, 1, 0, 0, 0, 0, 0, 0);
        }
        gemmS(W.Q1, W.K1, W.S1, L1_, (int)NC * 2);
        hipLaunchKernelGGL(mtop_kernel, dim3((int)NC * 2), dim3(128), 0, stream,
                           W.S1, idx1, W.top1, L1_, SK1_, U1_);
        hipLaunchKernelGGL(ctx_kernel, dim3((int)NC * 2 * U1_), dim3(256), 0, stream,
                           W.S1, W.top1, W.V1, W.CT1, L1_, U1_);
        if (use_mfma) {
            gM(W.CT1, W.w3_o1, a1ob, W.O1, (int)NC * U1_, 512, 512, 512, 512, (size_t)512 * 512, 0);
            gM(W.O1, W.w3_c2, c2b, W.H2, M2, 512, 2560, 512, 512, (size_t)512 * 2560, 1);
            gMqkv(W.H2, M2, W.w3_qkv2, a2qb, W.Q2, a2kb, W.K2, a2vb, W.V2);
        } else {
            gemm64(W.CT1, a1ow, a1ob, W.O1, (int)NC * U1_, 512, 512, 512, 512, 512, 1, 0, 0, 0, 0, 0, 0);
            gemm64(W.O1, W.w2t, c2b, W.H2, M2, 512, 2560, 512, 2560, 512, 1, 0, 0, 0, 0, 0, 1);
            gemm64(W.H2, a2qw, a2qb, W.Q2, M2, 512, 512, 512, 512, 512, 1, 0, 0, 0, 0, 0, 0);
            gemm64(W.H2, a2kw, a2kb, W.K2, M2, 512, 512, 512, 512, 512, 1, 0, 0, 0, 0, 0, 0);
            gemm64(W.H2, a2vw, a2vb, W.V2, M2, 512, 512, 512, 512, 512, 1, 0, 0, 0, 0, 0, 0);
        }
        gemmS(W.Q2, W.K2, W.S2, L2_, (int)NC * 2);
        hipLaunchKernelGGL(mtop_kernel, dim3((int)NC * 2), dim3(128), 0, stream,
                           W.S2, idx2, W.top2, L2_, SK2_, U2_);
        hipLaunchKernelGGL(ctx_kernel, dim3((int)NC * 2 * U2_), dim3(256), 0, stream,
                           W.S2, W.top2, W.V2, W.CT2, L2_, U2_);
        if (use_mfma) {
            gM(W.CT2, W.w3_o2, a2ob, W.O2 + (size_t)n0 * 12 * 512,
               (int)NC * U2_, 512, 512, 512, 512, (size_t)512 * 512, 0);
        } else {
            gemm64(W.CT2, a2ow, a2ob, W.O2 + (size_t)n0 * 12 * 512,
                   (int)NC * U2_, 512, 512, 512, 512, 512, 1, 0, 0, 0, 0, 0, 0);
        }
    }

    hipLaunchKernelGGL(ln_kernel, dim3(BT_), dim3(256), 0, stream, W.O2, lng, lnb);
    if (use_mfma) {
        gM(W.O2, W.w3_ih, W.biasG, W.Gx, BT_, NGATE_, DLN_, DLN_, NGATE_,
           (size_t)4096 * 6144, 0);
    } else {
        gemm64(W.O2, wih, W.biasG, W.Gx, BT_, NGATE_, DLN_, DLN_, DLN_, NGATE_, 1, 0, 0, 0, 0, 0, 0);
    }

    hipMemsetAsync(W.hbuf, 0, 2 * 16 * HC_ * sizeof(float), stream);
    hipMemsetAsync(W.cbuf, 0, 2 * 16 * HC_ * sizeof(float), stream);
    for (int t = 0; t < 48; ++t) {
        float* hp = W.hbuf + (t & 1) * 16 * HC_;
        float* hn = W.hbuf + ((t + 1) & 1) * 16 * HC_;
        float* cp = W.cbuf + (t & 1) * 16 * HC_;
        float* cn = W.cbuf + ((t + 1) & 1) * 16 * HC_;
        hipLaunchKernelGGL(lstm_step_kernel, dim3(128), dim3(256), 0, stream,
                           W.Gx, W.WhhT, hp, cp, hn, cn, t);
    }
    hipLaunchKernelGGL(final_kernel, dim3(16 * 24), dim3(64), 0, stream,
                       W.hbuf, finw, finb, out);
}

// Round 5
// 5079.247 us; speedup vs baseline: 1.8901x; 1.3390x over previous
//
#include <hip/hip_runtime.h>
#include <cfloat>
#include <cstdint>

// ---------------- problem constants ----------------
#define HID_   512
#define NH_    2
#define E_     256
#define L1_    100
#define SK1_   25
#define U1_    25
#define L2_    21
#define SK2_   12
#define U2_    12
#define BT_    768
#define DLN_   6144   // 12*HID
#define NGATE_ 4096   // 4*2*HID
#define HC_    1024   // 2*HID

typedef unsigned short u16;
typedef __attribute__((ext_vector_type(8))) short short8v;
typedef __attribute__((ext_vector_type(4))) short short4v;
typedef __attribute__((ext_vector_type(4))) float f32x4;

// ---- fp16 two-term split: x = h + l, |x-h-l| ~ 2^-22 |x| ----
__device__ __forceinline__ void split2_(float x, short& h, short& l) {
    _Float16 a = (_Float16)x;
    float r = x - (float)a;
    _Float16 b = (_Float16)r;
    union { _Float16 f; short s; } ua, ub;
    ua.f = a; ub.f = b;
    h = ua.s; l = ub.s;
}

// fp32 (N,K) -> two fp16 planes at dst[p*plane + off + i]
__global__ __launch_bounds__(256)
void cvt2_kernel(const float* __restrict__ src, u16* __restrict__ dst,
                 size_t n, size_t plane, size_t off)
{
    size_t i = ((size_t)blockIdx.x * 256 + threadIdx.x) * 4;
    if (i >= n) return;
    float4 v = *(const float4*)(src + i);
    float x[4] = {v.x, v.y, v.z, v.w};
    short h[4], l[4];
#pragma unroll
    for (int e = 0; e < 4; ++e) split2_(x[e], h[e], l[e]);
    *(short4v*)(dst + off + i)         = *(short4v*)h;
    *(short4v*)(dst + plane + off + i) = *(short4v*)l;
}

// XCD-bijective chunk map (m204) + 8-row supertile: consecutive logical
// blocks = consecutive row-blocks of one column panel, on one XCD's L2.
__device__ __forceinline__ void remap_block(int& bx, int& by, int gx, int gy)
{
    int nwg = gx * gy;
    int L = blockIdx.y * gx + blockIdx.x;      // HW linear order, x fastest
    int q = nwg >> 3, r = nwg & 7;
    int xcd = L & 7, pos = L >> 3;
    int logical = (xcd < r ? xcd * (q + 1) : r * (q + 1) + (xcd - r) * q) + pos;
    const int SH = 8;
    int full = gx / SH, rem = gx % SH;
    int fullBlocks = full * SH * gy;
    if (logical < fullBlocks) {
        int sr = logical / (SH * gy);
        int w  = logical % (SH * gy);
        by = w / SH;
        bx = sr * SH + (w % SH);
    } else {
        int w = logical - fullBlocks;
        by = w / rem;
        bx = full * SH + (w % rem);
    }
}

#define MFMA16_(acc, a, b) \
    asm volatile("v_mfma_f32_16x16x32_f16 %0, %1, %2, %0" : "+v"(acc) : "v"(a), "v"(b))

// =====================================================================
// MFMA GEMM (NT): Y[m,n] = X[m,:K] . W[n,:K] + bias[n]
// X fp32 (split in staging), W pre-split fp16 planes [2][Nw][K].
// 128x128 tile, BK=32, 4 waves (2x2), 16x16x32 f16 MFMA,
// 3-term product (hh,hl,lh) -> ~2^-22 relative accuracy.
// split!=0: N=1536 fused QKV.  conv_rows!=0: X row r -> (r/21)*25+r%21.
// =====================================================================
__global__ __launch_bounds__(256)
void gemm_mfma(const float* __restrict__ X, const u16* __restrict__ W3,
               const float* __restrict__ Ba, const float* __restrict__ Bb,
               const float* __restrict__ Bc,
               float* __restrict__ Ya, float* __restrict__ Yb, float* __restrict__ Yc,
               int M, int K, int ldx, int ldy, size_t wplane, int split, int conv_rows)
{
    __shared__ short Xs[2][128 * 32];
    __shared__ short Ws[2][128 * 32];
    const int tid = threadIdx.x;
    int bx, by;
    remap_block(bx, by, gridDim.x, gridDim.y);
    const int row0 = bx * 128;
    const int col0 = by * 128;
    const float* Bsel; float* Ysel; int coll;
    if (split) {
        int s = col0 >> 9;
        Bsel = (s == 0) ? Ba : ((s == 1) ? Bb : Bc);
        Ysel = (s == 0) ? Ya : ((s == 1) ? Yb : Yc);
        coll = col0 & 511;
    } else { Bsel = Ba; Ysel = Ya; coll = col0; }

    // staging mapping: thread -> (row 0..127, k-quad 0/16)
    const int srow = tid >> 1;
    const int skq = (tid & 1) * 16;
    int gr = row0 + srow; if (gr >= M) gr = M - 1;
    size_t xro = conv_rows ? ((size_t)(gr / 21) * 25 + (size_t)(gr % 21)) * (size_t)ldx
                           : (size_t)gr * (size_t)ldx;
    const float* xp = X + xro + skq;
    const u16* wp = W3 + (size_t)(col0 + srow) * (size_t)K + skq;
    const int sl0 = ((skq >> 3) + 0) ^ (srow & 3);   // swizzled 16B slots
    const int sl1 = ((skq >> 3) + 1) ^ (srow & 3);
    const int xw0 = srow * 32 + sl0 * 8;
    const int xw1 = srow * 32 + sl1 * 8;

    const int wave = tid >> 6, lane = tid & 63;
    const int wr = (wave >> 1) * 64, wc = (wave & 1) * 64;
    const int r16 = lane & 15, kb = lane >> 4;

    f32x4 acc[4][4];
#pragma unroll
    for (int i = 0; i < 4; ++i)
#pragma unroll
        for (int j = 0; j < 4; ++j) acc[i][j] = (f32x4){0.f, 0.f, 0.f, 0.f};

    for (int k0 = 0; k0 < K; k0 += 32) {
        float xv[16];
        *(float4*)&xv[0]  = *(const float4*)(xp + k0);
        *(float4*)&xv[4]  = *(const float4*)(xp + k0 + 4);
        *(float4*)&xv[8]  = *(const float4*)(xp + k0 + 8);
        *(float4*)&xv[12] = *(const float4*)(xp + k0 + 12);
        short hb[16], lb[16];
#pragma unroll
        for (int e = 0; e < 16; ++e) split2_(xv[e], hb[e], lb[e]);
        short8v wv[2][2];
#pragma unroll
        for (int p = 0; p < 2; ++p) {
            wv[p][0] = *(const short8v*)(wp + (size_t)p * wplane + k0);
            wv[p][1] = *(const short8v*)(wp + (size_t)p * wplane + k0 + 8);
        }
        __syncthreads();   // previous iteration's frag reads done
        *(short8v*)&Xs[0][xw0] = *(short8v*)&hb[0];
        *(short8v*)&Xs[0][xw1] = *(short8v*)&hb[8];
        *(short8v*)&Xs[1][xw0] = *(short8v*)&lb[0];
        *(short8v*)&Xs[1][xw1] = *(short8v*)&lb[8];
#pragma unroll
        for (int p = 0; p < 2; ++p) {
            *(short8v*)&Ws[p][xw0] = wv[p][0];
            *(short8v*)&Ws[p][xw1] = wv[p][1];
        }
        __syncthreads();
        short8v Bf[4][2];
#pragma unroll
        for (int j = 0; j < 4; ++j) {
            int c = wc + j * 16 + r16;
            int ad = c * 32 + ((kb ^ (c & 3)) * 8);
#pragma unroll
            for (int p = 0; p < 2; ++p) Bf[j][p] = *(short8v*)&Ws[p][ad];
        }
#pragma unroll
        for (int i = 0; i < 4; ++i) {
            int rrow = wr + i * 16 + r16;
            int ad = rrow * 32 + ((kb ^ (rrow & 3)) * 8);
            short8v Ah = *(short8v*)&Xs[0][ad];
            short8v Al = *(short8v*)&Xs[1][ad];
#pragma unroll
            for (int j = 0; j < 4; ++j) MFMA16_(acc[i][j], Ah, Bf[j][0]);   // h*h
#pragma unroll
            for (int j = 0; j < 4; ++j) MFMA16_(acc[i][j], Ah, Bf[j][1]);   // h*l
#pragma unroll
            for (int j = 0; j < 4; ++j) MFMA16_(acc[i][j], Al, Bf[j][0]);   // l*h
        }
    }
    asm volatile("s_nop 7\n\ts_nop 7" :::);   // MFMA -> VALU read hazard pad
    // epilogue: C/D layout col=lane&15, row=(lane>>4)*4+reg  [m89]
#pragma unroll
    for (int j = 0; j < 4; ++j) {
        int gc = coll + wc + j * 16 + r16;
        float bval = Bsel ? Bsel[gc] : 0.f;
#pragma unroll
        for (int i = 0; i < 4; ++i) {
#pragma unroll
            for (int r = 0; r < 4; ++r) {
                int grow = row0 + wr + i * 16 + kb * 4 + r;
                if (grow < M) Ysel[(size_t)grow * (size_t)ldy + gc] = acc[i][j][r] + bval;
            }
        }
    }
}

// =====================================================================
// batched MFMA scores: S[z] = Q[z] . K[z]^T  (L x L, K=256, head-sliced)
// one 4-wave WG per z; fp16x2 3-term; raw (unscaled) scores.
// =====================================================================
__global__ __launch_bounds__(256)
void scores_mfma(const float* __restrict__ Q, const float* __restrict__ Kx,
                 float* __restrict__ S, int L)
{
    __shared__ short Qs[2][128 * 32];
    __shared__ short Ks[2][128 * 32];
    const int tid = threadIdx.x;
    const int z = blockIdx.x;
    const int n = z >> 1, h = z & 1;
    const float* qb = Q + (size_t)n * L * HID_ + h * E_;
    const float* kbp = Kx + (size_t)n * L * HID_ + h * E_;
    const int srow = tid >> 1;
    const int skq = (tid & 1) * 16;
    const int cr = (srow < L) ? srow : (L - 1);
    const float* qp = qb + (size_t)cr * HID_ + skq;
    const float* kp = kbp + (size_t)cr * HID_ + skq;
    const int sl0 = ((skq >> 3) + 0) ^ (srow & 3);
    const int sl1 = ((skq >> 3) + 1) ^ (srow & 3);
    const int xw0 = srow * 32 + sl0 * 8;
    const int xw1 = srow * 32 + sl1 * 8;

    const int wave = tid >> 6, lane = tid & 63;
    const int wr = (wave >> 1) * 64, wc = (wave & 1) * 64;
    const int r16 = lane & 15, kb = lane >> 4;

    f32x4 acc[4][4];
#pragma unroll
    for (int i = 0; i < 4; ++i)
#pragma unroll
        for (int j = 0; j < 4; ++j) acc[i][j] = (f32x4){0.f, 0.f, 0.f, 0.f};

    for (int k0 = 0; k0 < E_; k0 += 32) {
        float qv[16], kv[16];
        *(float4*)&qv[0]  = *(const float4*)(qp + k0);
        *(float4*)&qv[4]  = *(const float4*)(qp + k0 + 4);
        *(float4*)&qv[8]  = *(const float4*)(qp + k0 + 8);
        *(float4*)&qv[12] = *(const float4*)(qp + k0 + 12);
        *(float4*)&kv[0]  = *(const float4*)(kp + k0);
        *(float4*)&kv[4]  = *(const float4*)(kp + k0 + 4);
        *(float4*)&kv[8]  = *(const float4*)(kp + k0 + 8);
        *(float4*)&kv[12] = *(const float4*)(kp + k0 + 12);
        short qh[16], ql[16], kh[16], kl[16];
#pragma unroll
        for (int e = 0; e < 16; ++e) { split2_(qv[e], qh[e], ql[e]); split2_(kv[e], kh[e], kl[e]); }
        __syncthreads();
        *(short8v*)&Qs[0][xw0] = *(short8v*)&qh[0];
        *(short8v*)&Qs[0][xw1] = *(short8v*)&qh[8];
        *(short8v*)&Qs[1][xw0] = *(short8v*)&ql[0];
        *(short8v*)&Qs[1][xw1] = *(short8v*)&ql[8];
        *(short8v*)&Ks[0][xw0] = *(short8v*)&kh[0];
        *(short8v*)&Ks[0][xw1] = *(short8v*)&kh[8];
        *(short8v*)&Ks[1][xw0] = *(short8v*)&kl[0];
        *(short8v*)&Ks[1][xw1] = *(short8v*)&kl[8];
        __syncthreads();
        short8v Bf[4][2];
#pragma unroll
        for (int j = 0; j < 4; ++j) {
            int c = wc + j * 16 + r16;
            int ad = c * 32 + ((kb ^ (c & 3)) * 8);
#pragma unroll
            for (int p = 0; p < 2; ++p) Bf[j][p] = *(short8v*)&Ks[p][ad];
        }
#pragma unroll
        for (int i = 0; i < 4; ++i) {
            int rrow = wr + i * 16 + r16;
            int ad = rrow * 32 + ((kb ^ (rrow & 3)) * 8);
            short8v Ah = *(short8v*)&Qs[0][ad];
            short8v Al = *(short8v*)&Qs[1][ad];
#pragma unroll
            for (int j = 0; j < 4; ++j) MFMA16_(acc[i][j], Ah, Bf[j][0]);
#pragma unroll
            for (int j = 0; j < 4; ++j) MFMA16_(acc[i][j], Ah, Bf[j][1]);
#pragma unroll
            for (int j = 0; j < 4; ++j) MFMA16_(acc[i][j], Al, Bf[j][0]);
        }
    }
    asm volatile("s_nop 7\n\ts_nop 7" :::);
#pragma unroll
    for (int j = 0; j < 4; ++j) {
        int gc = wc + j * 16 + r16;
        if (gc >= L) continue;
#pragma unroll
        for (int i = 0; i < 4; ++i) {
#pragma unroll
            for (int r = 0; r < 4; ++r) {
                int grow = wr + i * 16 + kb * 4 + r;
                if (grow < L) S[((size_t)z * L + grow) * L + gc] = acc[i][j][r];
            }
        }
    }
}

// =====================================================================
// fp32 64x64 GEMM (S2 scores + full fallback path). NT, z-batched,
// optional conv2 window remap.
// =====================================================================
__global__ __launch_bounds__(256)
void gemm_kernel(const float* __restrict__ X, const float* __restrict__ W,
                 const float* __restrict__ bias, float* __restrict__ Y,
                 int M, int N, int K, int ldx, int ldw, int ldy,
                 size_t bxn, size_t bxh, size_t bwn, size_t bwh, size_t byz,
                 int conv_rows)
{
    __shared__ __align__(16) float Xs[16][68];
    __shared__ __align__(16) float Ws[16][68];
    const int tid = threadIdx.x;
    const int z = blockIdx.z;
    const float* Xb = X + (size_t)(z >> 1) * bxn + (size_t)(z & 1) * bxh;
    const float* Wb = W + (size_t)(z >> 1) * bwn + (size_t)(z & 1) * bwh;
    float* Yb = Y + (size_t)z * byz;
    const int row0 = blockIdx.x * 64;
    const int col0 = blockIdx.y * 64;
    const int lr = tid >> 4;
    const int lc = tid & 15;
    float acc[4][4] = {{0.f}};
    for (int k0 = 0; k0 < K; k0 += 16) {
#pragma unroll
        for (int p = 0; p < 4; ++p) {
            int r = lr + p * 16;
            int grr = row0 + r;
            int gcc = col0 + r;
            float xv = 0.f, wvv = 0.f;
            if (grr < M) {
                size_t ro = conv_rows ? ((size_t)(grr / 21) * 25 + (size_t)(grr % 21)) * (size_t)ldx
                                      : (size_t)grr * (size_t)ldx;
                xv = Xb[ro + k0 + lc];
            }
            if (gcc < N) wvv = Wb[(size_t)gcc * (size_t)ldw + k0 + lc];
            Xs[lc][r] = xv;
            Ws[lc][r] = wvv;
        }
        __syncthreads();
#pragma unroll
        for (int k = 0; k < 16; ++k) {
            float4 a4 = *reinterpret_cast<const float4*>(&Xs[k][lr * 4]);
            float4 b4 = *reinterpret_cast<const float4*>(&Ws[k][lc * 4]);
            float a[4] = {a4.x, a4.y, a4.z, a4.w};
            float b[4] = {b4.x, b4.y, b4.z, b4.w};
#pragma unroll
            for (int i = 0; i < 4; ++i)
#pragma unroll
                for (int j = 0; j < 4; ++j)
                    acc[i][j] += a[i] * b[j];
        }
        __syncthreads();
    }
#pragma unroll
    for (int i = 0; i < 4; ++i) {
        int grr = row0 + lr * 4 + i;
        if (grr >= M) continue;
#pragma unroll
        for (int j = 0; j < 4; ++j) {
            int gcc = col0 + lc * 4 + j;
            if (gcc >= N) continue;
            float v = acc[i][j];
            if (bias) v += bias[gcc];
            Yb[(size_t)grr * (size_t)ldy + gcc] = v;
        }
    }
}

// =====================================================================
// conv1: input (768,104,10,8) select wt + positional enc -> VALID conv K=5
// =====================================================================
__global__ __launch_bounds__(256)
void conv1_kernel(const float* __restrict__ input, const int* __restrict__ wtp,
                  const float* __restrict__ w, const float* __restrict__ bias,
                  float* __restrict__ H, int n0)
{
    __shared__ float xs[50];
    const int bid = blockIdx.x;
    const int nloc = bid / L1_;
    const int l = bid % L1_;
    const size_t n = (size_t)n0 + nloc;
    const int tid = threadIdx.x;
    if (tid < 50) {
        int i = tid / 5, k = tid % 5;
        int t = l + k;
        float xv;
        if (i < 8) {
            xv = input[((n * 104 + t) * 10 + wtp[0]) * 8 + i];
        } else {
            float pos = (float)t / 104.0f;
            xv = (i == 8) ? sinf(pos) : cosf(pos);
        }
        xs[i * 5 + k] = xv;
    }
    __syncthreads();
    for (int o = tid; o < HID_; o += 256) {
        const float* wr = w + (size_t)o * 50;
        float acc = bias[o];
#pragma unroll
        for (int j = 0; j < 50; ++j) acc += wr[j] * xs[j];
        H[((size_t)nloc * L1_ + l) * HID_ + o] = acc;
    }
}

// =====================================================================
// sparsity measure m + stable descending top-U (matches jax.lax.top_k)
// =====================================================================
__global__ __launch_bounds__(128)
void mtop_kernel(const float* __restrict__ S, const int* __restrict__ idx,
                 int* __restrict__ top, int L, int SK, int U)
{
    __shared__ float mv[128];
    __shared__ float rv[128];
    __shared__ int   ri[128];
    const int z = blockIdx.x;
    const int tid = threadIdx.x;
    float m = -FLT_MAX;
    if (tid < L) {
        const float* row = S + ((size_t)z * L + tid) * L;
        float mx = -FLT_MAX, sm = 0.f;
        for (int s = 0; s < SK; ++s) {
            float v = row[idx[tid * SK + s]];
            mx = fmaxf(mx, v);
            sm += v;
        }
        m = mx - sm / (float)L;
    }
    mv[tid] = m;
    __syncthreads();
    for (int u = 0; u < U; ++u) {
        rv[tid] = mv[tid]; ri[tid] = tid;
        __syncthreads();
        for (int off = 64; off > 0; off >>= 1) {
            if (tid < off) {
                float v2 = rv[tid + off]; int i2 = ri[tid + off];
                if (v2 > rv[tid] || (v2 == rv[tid] && i2 < ri[tid])) { rv[tid] = v2; ri[tid] = i2; }
            }
            __syncthreads();
        }
        if (tid == 0) { top[(size_t)z * U + u] = ri[0]; mv[ri[0]] = -FLT_MAX; }
        __syncthreads();
    }
}

// =====================================================================
// softmax(selected row) -> suffix-sum weights -> dot raw V
// (attn @ cumsum(V) == suffix_sum(attn) @ V) ; .view() interleave output
// =====================================================================
__global__ __launch_bounds__(256)
void ctx_kernel(const float* __restrict__ S, const int* __restrict__ top,
                const float* __restrict__ V, float* __restrict__ C,
                int L, int U)
{
    __shared__ float attn[128];
    __shared__ float red[256];
    const int bid = blockIdx.x;
    const int u = bid % U;
    const int rem = bid / U;
    const int h = rem & 1;
    const int n = rem >> 1;
    const int tid = threadIdx.x;
    const int z = n * 2 + h;
    const int r = top[(size_t)z * U + u];
    const float* srow = S + ((size_t)z * L + r) * L;
    float v = (tid < L) ? srow[tid] * 0.0625f : -FLT_MAX;   // 1/sqrt(256)
    red[tid] = v;
    __syncthreads();
    for (int off = 128; off > 0; off >>= 1) { if (tid < off) red[tid] = fmaxf(red[tid], red[tid + off]); __syncthreads(); }
    float mx = red[0];
    __syncthreads();
    float e = (tid < L) ? expf(v - mx) : 0.f;
    red[tid] = e;
    __syncthreads();
    for (int off = 128; off > 0; off >>= 1) { if (tid < off) red[tid] += red[tid + off]; __syncthreads(); }
    float inv = 1.f / red[0];
    if (tid < 128) attn[tid] = (tid < L) ? e * inv : 0.f;
    __syncthreads();
    for (int off = 1; off < 128; off <<= 1) {
        float add = 0.f;
        if (tid < 128 && tid + off < 128) add = attn[tid + off];
        __syncthreads();
        if (tid < 128) attn[tid] += add;
        __syncthreads();
    }
    float acc = 0.f;
    const float* vb = V + (size_t)n * L * HID_ + h * E_ + tid;
    for (int s = 0; s < L; ++s) acc += attn[s] * vb[(size_t)s * HID_];
    int slot = h * U + u;
    int rr = slot >> 1, cc = (slot & 1) * E_ + tid;
    C[((size_t)n * U + rr) * HID_ + cc] = acc;
}

// 32x32 tiled transpose: A (R,C) -> At (C,R)
__global__ __launch_bounds__(256)
void transpose_kernel(const float* __restrict__ A, float* __restrict__ At, int R, int C)
{
    __shared__ float ts[32][33];
    int cb = blockIdx.x * 32, rb = blockIdx.y * 32;
    int tx = threadIdx.x & 31, ty = threadIdx.x >> 5;
    for (int i = ty; i < 32; i += 8) ts[i][tx] = A[(size_t)(rb + i) * C + cb + tx];
    __syncthreads();
    for (int i = ty; i < 32; i += 8) At[(size_t)(cb + i) * R + rb + tx] = ts[tx][i];
}

// conv2 weight (O,I,K) -> (O,K,I)
__global__ void w2t_kernel(const float* __restrict__ w, float* __restrict__ wt)
{
    int idx = blockIdx.x * 256 + threadIdx.x;
    if (idx >= 512 * 5 * 512) return;
    int i = idx & 511;
    int rem = idx >> 9;
    int k = rem % 5;
    int o = rem / 5;
    wt[idx] = w[((size_t)o * 512 + i) * 5 + k];
}

__global__ void biasg_kernel(const float* __restrict__ a, const float* __restrict__ b, float* __restrict__ o)
{
    int i = blockIdx.x * 256 + threadIdx.x;
    if (i < NGATE_) o[i] = a[i] + b[i];
}

// LayerNorm(6144) in place; one block per row
__global__ __launch_bounds__(256)
void ln_kernel(float* __restrict__ X, const float* __restrict__ g, const float* __restrict__ b)
{
    __shared__ float lred[4];
    const int row = blockIdx.x;
    const int tid = threadIdx.x;
    float* x = X + (size_t)row * DLN_;
    float v[24];
#pragma unroll
    for (int i = 0; i < 24; ++i) v[i] = x[tid + i * 256];
    float s = 0.f;
#pragma unroll
    for (int i = 0; i < 24; ++i) s += v[i];
    for (int off = 32; off > 0; off >>= 1) s += __shfl_down(s, off);
    int lane = tid & 63, wid = tid >> 6;
    if (lane == 0) lred[wid] = s;
    __syncthreads();
    float mu = (lred[0] + lred[1] + lred[2] + lred[3]) / (float)DLN_;
    float q = 0.f;
#pragma unroll
    for (int i = 0; i < 24; ++i) { float d = v[i] - mu; q += d * d; }
    for (int off = 32; off > 0; off >>= 1) q += __shfl_down(q, off);
    __syncthreads();
    if (lane == 0) lred[wid] = q;
    __syncthreads();
    float var = (lred[0] + lred[1] + lred[2] + lred[3]) / (float)DLN_;
    float rstd = 1.0f / sqrtf(var + 1e-5f);
#pragma unroll
    for (int i = 0; i < 24; ++i) {
        int c = tid + i * 256;
        x[c] = (v[i] - mu) * rstd * g[c] + b[c];
    }
}

// =====================================================================
// one LSTM time step
// =====================================================================
__global__ __launch_bounds__(256)
void lstm_step_kernel(const float* __restrict__ Gx, const float* __restrict__ WhhT,
                      const float* __restrict__ hp, const float* __restrict__ cp,
                      float* __restrict__ hn, float* __restrict__ cn, int t)
{
    __shared__ __align__(16) float hs[16 * HC_];
    __shared__ float pbuf[4096];
    const int tid = threadIdx.x;
    {
        const float4* hp4 = (const float4*)hp;
        float4* hs4 = (float4*)hs;
        for (int i = tid; i < 16 * HC_ / 4; i += 256) hs4[i] = hp4[i];
    }
    __syncthreads();
    const int jjl = tid & 7;
    const int g = (tid >> 3) & 3;
    const int ks = tid >> 5;
    const int jj = blockIdx.x * 8 + jjl;
    float acc[16];
#pragma unroll
    for (int b = 0; b < 16; ++b) acc[b] = 0.f;
    const float* wp = WhhT + (size_t)(ks * 128) * NGATE_ + (size_t)g * HC_ + jj;
    const float* hb = hs + ks * 128;
    for (int k = 0; k < 128; ++k) {
        float w = wp[(size_t)k * NGATE_];
#pragma unroll
        for (int b = 0; b < 16; ++b) acc[b] += hb[b * HC_ + k] * w;
    }
#pragma unroll
    for (int b = 0; b < 16; ++b) pbuf[((g * 8 + jjl) * 16 + b) * 8 + ks] = acc[b];
    __syncthreads();
    if (tid < 128) {
        int b = tid >> 3, jl = tid & 7;
        int jjo = blockIdx.x * 8 + jl;
        float G[4];
#pragma unroll
        for (int g2 = 0; g2 < 4; ++g2) {
            float s = 0.f;
#pragma unroll
            for (int k2 = 0; k2 < 8; ++k2) s += pbuf[((g2 * 8 + jl) * 16 + b) * 8 + k2];
            G[g2] = s + Gx[((size_t)(b * 48 + t)) * NGATE_ + g2 * HC_ + jjo];
        }
        float ig = 1.f / (1.f + expf(-G[0]));
        float fg = 1.f / (1.f + expf(-G[1]));
        float gg = tanhf(G[2]);
        float og = 1.f / (1.f + expf(-G[3]));
        float c = fg * cp[b * HC_ + jjo] + ig * gg;
        float h = og * tanhf(c);
        cn[b * HC_ + jjo] = c;
        hn[b * HC_ + jjo] = h;
    }
}

__global__ __launch_bounds__(64)
void final_kernel(const float* __restrict__ hn, const float* __restrict__ W,
                  const float* __restrict__ bias, float* __restrict__ out)
{
    int o = blockIdx.x;
    int bb = o / 24, p = o % 24;
    int lane = threadIdx.x;
    float acc = 0.f;
    for (int k = lane; k < HC_; k += 64) acc += hn[(size_t)bb * HC_ + k] * W[(size_t)p * HC_ + k];
    for (int off = 32; off > 0; off >>= 1) acc += __shfl_down(acc, off);
    if (lane == 0) out[o] = acc + bias[p];
}

// ---------------------------------------------------------------------
struct WSLayout {
    float *O2, *Gx, *WhhT, *w2t, *biasG, *hbuf, *cbuf;
    float *H1, *Q1, *K1, *V1, *S1, *CT1, *O1;
    float *H2, *Q2, *K2, *V2, *S2, *CT2;
    int *top1, *top2;
    u16 *w3_qkv1, *w3_o1, *w3_c2, *w3_qkv2, *w3_o2, *w3_ih;
};

static size_t ws_layout(char* base, size_t NC, int with_w3, WSLayout& w)
{
    size_t off = 0;
    auto A = [&](size_t nfloats) -> float* {
        float* p = (float*)(base + off);
        off += ((nfloats * 4 + 255) & ~(size_t)255);
        return p;
    };
    auto AU = [&](size_t nush) -> u16* {
        u16* p = (u16*)(base + off);
        off += ((nush * 2 + 255) & ~(size_t)255);
        return p;
    };
    if (with_w3) {
        w.w3_qkv1 = AU((size_t)2 * 1536 * 512);
        w.w3_o1   = AU((size_t)2 * 512 * 512);
        w.w3_c2   = AU((size_t)2 * 512 * 2560);
        w.w3_qkv2 = AU((size_t)2 * 1536 * 512);
        w.w3_o2   = AU((size_t)2 * 512 * 512);
        w.w3_ih   = AU((size_t)2 * 4096 * 6144);
    } else {
        w.w3_qkv1 = w.w3_o1 = w.w3_c2 = w.w3_qkv2 = w.w3_o2 = w.w3_ih = nullptr;
    }
    w.O2 = A((size_t)BT_ * 12 * 512);
    w.Gx = A((size_t)BT_ * NGATE_);
    w.WhhT = A((size_t)HC_ * NGATE_);
    w.w2t = A((size_t)512 * 5 * 512);
    w.biasG = A(NGATE_);
    w.hbuf = A(2 * 16 * HC_);
    w.cbuf = A(2 * 16 * HC_);
    w.H1 = A(NC * 51200); w.Q1 = A(NC * 51200); w.K1 = A(NC * 51200); w.V1 = A(NC * 51200);
    w.S1 = A(NC * 20000); w.CT1 = A(NC * 12800); w.O1 = A(NC * 12800);
    w.H2 = A(NC * 10752); w.Q2 = A(NC * 10752); w.K2 = A(NC * 10752); w.V2 = A(NC * 10752);
    w.S2 = A(NC * 882);  w.CT2 = A(NC * 6144);
    w.top1 = (int*)A(NC * 50);
    w.top2 = (int*)A(NC * 24);
    return off;
}

extern "C" void kernel_launch(void* const* d_in, const int* in_sizes, int n_in,
                              void* d_out, int out_size, void* d_ws, size_t ws_size,
                              hipStream_t stream)
{
    const float* input = (const float*)d_in[0];
    const int*   wtp   = (const int*)d_in[2];
    const int*   idx1  = (const int*)d_in[3];
    const int*   idx2  = (const int*)d_in[4];
    const float* c1w   = (const float*)d_in[5];
    const float* c1b   = (const float*)d_in[6];
    const float* c2w   = (const float*)d_in[7];
    const float* c2b   = (const float*)d_in[8];
    const float* a1qw = (const float*)d_in[9];  const float* a1qb = (const float*)d_in[10];
    const float* a1kw = (const float*)d_in[11]; const float* a1kb = (const float*)d_in[12];
    const float* a1vw = (const float*)d_in[13]; const float* a1vb = (const float*)d_in[14];
    const float* a1ow = (const float*)d_in[15]; const float* a1ob = (const float*)d_in[16];
    const float* a2qw = (const float*)d_in[17]; const float* a2qb = (const float*)d_in[18];
    const float* a2kw = (const float*)d_in[19]; const float* a2kb = (const float*)d_in[20];
    const float* a2vw = (const float*)d_in[21]; const float* a2vb = (const float*)d_in[22];
    const float* a2ow = (const float*)d_in[23]; const float* a2ob = (const float*)d_in[24];
    const float* lng  = (const float*)d_in[25]; const float* lnb = (const float*)d_in[26];
    const float* wih  = (const float*)d_in[27]; const float* whh = (const float*)d_in[28];
    const float* bih  = (const float*)d_in[29]; const float* bhh = (const float*)d_in[30];
    const float* finw = (const float*)d_in[31]; const float* finb = (const float*)d_in[32];
    float* out = (float*)d_out;

    static const size_t cand[5] = {768, 384, 192, 128, 64};
    size_t NC = 64;
    int use_mfma = 0;
    WSLayout W;
    for (int i = 0; i < 5; ++i) {
        WSLayout tmp;
        if (ws_layout((char*)d_ws, cand[i], 1, tmp) <= ws_size) { NC = cand[i]; use_mfma = 1; break; }
    }
    if (!use_mfma) {
        for (int i = 0; i < 5; ++i) {
            WSLayout tmp;
            if (ws_layout((char*)d_ws, cand[i], 0, tmp) <= ws_size) { NC = cand[i]; break; }
        }
    }
    ws_layout((char*)d_ws, NC, use_mfma, W);

    auto gemm64 = [&](const float* X, const float* Wt, const float* bias, float* Y,
                      int M, int N, int K, int ldx, int ldw, int ldy,
                      int Z, size_t bxn, size_t bxh, size_t bwn, size_t bwh, size_t byz,
                      int conv_rows) {
        dim3 grid((M + 63) / 64, (N + 63) / 64, Z);
        hipLaunchKernelGGL(gemm_kernel, grid, dim3(256), 0, stream,
                           X, Wt, bias, Y, M, N, K, ldx, ldw, ldy,
                           bxn, bxh, bwn, bwh, byz, conv_rows);
    };
    auto gemmS = [&](const float* X, const float* Wt, float* Y, int L, int Z) {
        dim3 grid((L + 63) / 64, (L + 63) / 64, Z);
        hipLaunchKernelGGL(gemm_kernel, grid, dim3(256), 0, stream,
                           X, Wt, nullptr, Y, L, L, E_, 512, 512, L,
                           (size_t)L * 512, E_, (size_t)L * 512, E_, (size_t)L * L, 0);
    };
    auto cvt2 = [&](const float* src, u16* dst, size_t n, size_t plane, size_t off) {
        hipLaunchKernelGGL(cvt2_kernel, dim3((unsigned)((n / 4 + 255) / 256)), dim3(256), 0, stream,
                           src, dst, n, plane, off);
    };
    auto gM = [&](const float* X, const u16* W3, const float* bias, float* Y,
                  int M, int N, int K, int ldx, int ldy, size_t wplane, int conv_rows) {
        dim3 grid((M + 127) / 128, N / 128, 1);
        hipLaunchKernelGGL(gemm_mfma, grid, dim3(256), 0, stream,
                           X, W3, bias, nullptr, nullptr, Y, nullptr, nullptr,
                           M, K, ldx, ldy, wplane, 0, conv_rows);
    };
    auto gMqkv = [&](const float* X, int M, const u16* W3,
                     const float* bq, float* Q, const float* bk, float* Kx,
                     const float* bv, float* V) {
        dim3 grid((M + 127) / 128, 1536 / 128, 1);
        hipLaunchKernelGGL(gemm_mfma, grid, dim3(256), 0, stream,
                           X, W3, bq, bk, bv, Q, Kx, V,
                           M, 512, 512, 512, (size_t)1536 * 512, 1, 0);
    };

    // ---- one-time (per call) prep ----
    hipLaunchKernelGGL(transpose_kernel, dim3(HC_ / 32, NGATE_ / 32), dim3(256), 0, stream,
                       whh, W.WhhT, NGATE_, HC_);
    hipLaunchKernelGGL(w2t_kernel, dim3((512 * 5 * 512 + 255) / 256), dim3(256), 0, stream, c2w, W.w2t);
    hipLaunchKernelGGL(biasg_kernel, dim3((NGATE_ + 255) / 256), dim3(256), 0, stream, bih, bhh, W.biasG);
    if (use_mfma) {
        const size_t p512 = (size_t)512 * 512, pq = (size_t)1536 * 512;
        cvt2(a1qw, W.w3_qkv1, p512, pq, 0);
        cvt2(a1kw, W.w3_qkv1, p512, pq, p512);
        cvt2(a1vw, W.w3_qkv1, p512, pq, 2 * p512);
        cvt2(a1ow, W.w3_o1, p512, p512, 0);
        cvt2(W.w2t, W.w3_c2, (size_t)512 * 2560, (size_t)512 * 2560, 0);
        cvt2(a2qw, W.w3_qkv2, p512, pq, 0);
        cvt2(a2kw, W.w3_qkv2, p512, pq, p512);
        cvt2(a2vw, W.w3_qkv2, p512, pq, 2 * p512);
        cvt2(a2ow, W.w3_o2, p512, p512, 0);
        cvt2(wih, W.w3_ih, (size_t)4096 * 6144, (size_t)4096 * 6144, 0);
    }

    const int nchunks = BT_ / (int)NC;
    for (int ch = 0; ch < nchunks; ++ch) {
        const int n0 = ch * (int)NC;
        const int M1 = (int)NC * L1_;
        const int M2 = (int)NC * L2_;
        hipLaunchKernelGGL(conv1_kernel, dim3((int)NC * L1_), dim3(256), 0, stream,
                           input, wtp, c1w, c1b, W.H1, n0);
        if (use_mfma) {
            gMqkv(W.H1, M1, W.w3_qkv1, a1qb, W.Q1, a1kb, W.K1, a1vb, W.V1);
            hipLaunchKernelGGL(scores_mfma, dim3((int)NC * 2), dim3(256), 0, stream,
                               W.Q1, W.K1, W.S1, L1_);
        } else {
            gemm64(W.H1, a1qw, a1qb, W.Q1, M1, 512, 512, 512, 512, 512, 1, 0, 0, 0, 0, 0, 0);
            gemm64(W.H1, a1kw, a1kb, W.K1, M1, 512, 512, 512, 512, 512, 1, 0, 0, 0, 0, 0, 0);
            gemm64(W.H1, a1vw, a1vb, W.V1, M1, 512, 512, 512, 512, 512, 1, 0, 0, 0, 0, 0, 0);
            gemmS(W.Q1, W.K1, W.S1, L1_, (int)NC * 2);
        }
        hipLaunchKernelGGL(mtop_kernel, dim3((int)NC * 2), dim3(128), 0, stream,
                           W.S1, idx1, W.top1, L1_, SK1_, U1_);
        hipLaunchKernelGGL(ctx_kernel, dim3((int)NC * 2 * U1_), dim3(256), 0, stream,
                           W.S1, W.top1, W.V1, W.CT1, L1_, U1_);
        if (use_mfma) {
            gM(W.CT1, W.w3_o1, a1ob, W.O1, (int)NC * U1_, 512, 512, 512, 512, (size_t)512 * 512, 0);
            gM(W.O1, W.w3_c2, c2b, W.H2, M2, 512, 2560, 512, 512, (size_t)512 * 2560, 1);
            gMqkv(W.H2, M2, W.w3_qkv2, a2qb, W.Q2, a2kb, W.K2, a2vb, W.V2);
        } else {
            gemm64(W.CT1, a1ow, a1ob, W.O1, (int)NC * U1_, 512, 512, 512, 512, 512, 1, 0, 0, 0, 0, 0, 0);
            gemm64(W.O1, W.w2t, c2b, W.H2, M2, 512, 2560, 512, 2560, 512, 1, 0, 0, 0, 0, 0, 1);
            gemm64(W.H2, a2qw, a2qb, W.Q2, M2, 512, 512, 512, 512, 512, 1, 0, 0, 0, 0, 0, 0);
            gemm64(W.H2, a2kw, a2kb, W.K2, M2, 512, 512, 512, 512, 512, 1, 0, 0, 0, 0, 0, 0);
            gemm64(W.H2, a2vw, a2vb, W.V2, M2, 512, 512, 512, 512, 512, 1, 0, 0, 0, 0, 0, 0);
        }
        gemmS(W.Q2, W.K2, W.S2, L2_, (int)NC * 2);
        hipLaunchKernelGGL(mtop_kernel, dim3((int)NC * 2), dim3(128), 0, stream,
                           W.S2, idx2, W.top2, L2_, SK2_, U2_);
        hipLaunchKernelGGL(ctx_kernel, dim3((int)NC * 2 * U2_), dim3(256), 0, stream,
                           W.S2, W.top2, W.V2, W.CT2, L2_, U2_);
        if (use_mfma) {
            gM(W.CT2, W.w3_o2, a2ob, W.O2 + (size_t)n0 * 12 * 512,
               (int)NC * U2_, 512, 512, 512, 512, (size_t)512 * 512, 0);
        } else {
            gemm64(W.CT2, a2ow, a2ob, W.O2 + (size_t)n0 * 12 * 512,
                   (int)NC * U2_, 512, 512, 512, 512, 512, 1, 0, 0, 0, 0, 0, 0);
        }
    }

    hipLaunchKernelGGL(ln_kernel, dim3(BT_), dim3(256), 0, stream, W.O2, lng, lnb);
    if (use_mfma) {
        gM(W.O2, W.w3_ih, W.biasG, W.Gx, BT_, NGATE_, DLN_, DLN_, NGATE_,
           (size_t)4096 * 6144, 0);
    } else {
        gemm64(W.O2, wih, W.biasG, W.Gx, BT_, NGATE_, DLN_, DLN_, DLN_, NGATE_, 1, 0, 0, 0, 0, 0, 0);
    }

    hipMemsetAsync(W.hbuf, 0, 2 * 16 * HC_ * sizeof(float), stream);
    hipMemsetAsync(W.cbuf, 0, 2 * 16 * HC_ * sizeof(float), stream);
    for (int t = 0; t < 48; ++t) {
        float* hp = W.hbuf + (t & 1) * 16 * HC_;
        float* hn = W.hbuf + ((t + 1) & 1) * 16 * HC_;
        float* cp = W.cbuf + (t & 1) * 16 * HC_;
        float* cn = W.cbuf + ((t + 1) & 1) * 16 * HC_;
        hipLaunchKernelGGL(lstm_step_kernel, dim3(128), dim3(256), 0, stream,
                           W.Gx, W.WhhT, hp, cp, hn, cn, t);
    }
    hipLaunchKernelGGL(final_kernel, dim3(16 * 24), dim3(64), 0, stream,
                       W.hbuf, finw, finb, out);
}